// Round 15
// baseline (1174.616 us; speedup 1.0000x reference)
//
#include <hip/hip_runtime.h>
#include <hip/hip_bf16.h>
#include <hip/hip_fp16.h>

#define WPB 4          // waves per block (256 threads)
#define SCAN_EPB 1024  // elements per scan block (256 thr x 4)
#define PLACE_NB 4     // sequential destination-range passes for CSR placement
#define NBUCK 32       // degree buckets for row batching

typedef _Float16 h8 __attribute__((ext_vector_type(8)));
typedef float f32x4 __attribute__((ext_vector_type(4)));

__device__ __forceinline__ float bcast(float v, int i) {
  return __builtin_bit_cast(float, __builtin_amdgcn_readlane(__builtin_bit_cast(int, v), i));
}
__device__ __forceinline__ h8 h8zero() {
  h8 r;
#pragma unroll
  for (int j = 0; j < 8; ++j) r[j] = (_Float16)0;
  return r;
}
__device__ __forceinline__ h8 cvt8(float4 a, float4 b) {
  h8 r;
  r[0] = (_Float16)a.x; r[1] = (_Float16)a.y; r[2] = (_Float16)a.z; r[3] = (_Float16)a.w;
  r[4] = (_Float16)b.x; r[5] = (_Float16)b.y; r[6] = (_Float16)b.z; r[7] = (_Float16)b.w;
  return r;
}

// ---------------- encoders ----------------
// out = tanh(x @ W1^T + b1) @ W2^T + b2. One row per wave; W in VGPRs; f16 output.
// Persistent capped grid (R9: full grids replicate the W->VGPR preamble, 2.3x slower).
template<int IN_F>
__global__ __launch_bounds__(256, 4) void encoder_kernel(
    const float* __restrict__ x,
    const float* __restrict__ W1, const float* __restrict__ b1,
    const float* __restrict__ W2, const float* __restrict__ b2,
    __half* __restrict__ out, int n_rows) {
  int t = threadIdx.x;
  int wave = t >> 6, lane = t & 63;

  float w1reg[IN_F];
#pragma unroll
  for (int j = 0; j < IN_F; ++j) w1reg[j] = W1[lane * IN_F + j];
  float w2reg[64];
  const float4* W24 = (const float4*)(W2 + (size_t)lane * 64);
#pragma unroll
  for (int i = 0; i < 16; ++i) {
    float4 w = W24[i];
    w2reg[4 * i] = w.x; w2reg[4 * i + 1] = w.y;
    w2reg[4 * i + 2] = w.z; w2reg[4 * i + 3] = w.w;
  }
  float b1v = b1[lane], b2v = b2[lane];

  int stride = gridDim.x * WPB;
  for (int row = blockIdx.x * WPB + wave; row < n_rows; row += stride) {
    float xl = 0.0f;
    if (lane < IN_F) xl = x[(size_t)row * IN_F + lane];
    float h = b1v;
#pragma unroll
    for (int j = 0; j < IN_F; ++j) h += w1reg[j] * bcast(xl, j);
    float hid = tanhf(h);

    float o0 = b2v, o1 = 0.f, o2 = 0.f, o3 = 0.f;
#pragma unroll
    for (int i = 0; i < 64; i += 4) {
      o0 += w2reg[i]     * bcast(hid, i);
      o1 += w2reg[i + 1] * bcast(hid, i + 1);
      o2 += w2reg[i + 2] * bcast(hid, i + 2);
      o3 += w2reg[i + 3] * bcast(hid, i + 3);
    }
    out[(size_t)row * 64 + lane] = __float2half((o0 + o1) + (o2 + o3));
  }
}

// ---------------- CSR build ----------------
// The single scattered-atomic pass (transaction-floor ~26 G/s) also emits
// per-edge ranks, making placement atomic-free.
__global__ __launch_bounds__(256) void hist_rank_kernel(
    const int* __restrict__ ev, const int* __restrict__ ec,
    int* __restrict__ deg_v, int* __restrict__ deg_c,
    int* __restrict__ rank_v, int* __restrict__ rank_c, int n_edges) {
  int e = blockIdx.x * 256 + threadIdx.x;
  if (e >= n_edges) return;
  rank_v[e] = atomicAdd(&deg_v[ev[e]], 1);
  rank_c[e] = atomicAdd(&deg_c[ec[e]], 1);
}

__global__ __launch_bounds__(256) void scan_blocks_kernel(
    const int* __restrict__ in, int* __restrict__ out,
    int* __restrict__ bsums, int n) {
  __shared__ int s[256];
  int t = threadIdx.x;
  int base = blockIdx.x * SCAN_EPB + t * 4;
  int v[4]; int local = 0;
#pragma unroll
  for (int j = 0; j < 4; ++j) {
    int idx = base + j;
    v[j] = (idx < n) ? in[idx] : 0;
    local += v[j];
  }
  s[t] = local;
  __syncthreads();
  for (int off = 1; off < 256; off <<= 1) {
    int val = (t >= off) ? s[t - off] : 0;
    __syncthreads();
    s[t] += val;
    __syncthreads();
  }
  int run = s[t] - local;
#pragma unroll
  for (int j = 0; j < 4; ++j) {
    int idx = base + j;
    if (idx < n) out[idx] = run;
    run += v[j];
  }
  if (t == 255) bsums[blockIdx.x] = s[255];
}

__global__ __launch_bounds__(256) void scan_sums_kernel(int* __restrict__ bsums, int nb) {
  __shared__ int s[256];
  int t = threadIdx.x;
  int base = t * 4;
  int v[4]; int local = 0;
#pragma unroll
  for (int j = 0; j < 4; ++j) {
    int idx = base + j;
    v[j] = (idx < nb) ? bsums[idx] : 0;
    local += v[j];
  }
  s[t] = local;
  __syncthreads();
  for (int off = 1; off < 256; off <<= 1) {
    int val = (t >= off) ? s[t - off] : 0;
    __syncthreads();
    s[t] += val;
    __syncthreads();
  }
  int run = s[t] - local;
#pragma unroll
  for (int j = 0; j < 4; ++j) {
    int idx = base + j;
    if (idx < nb) bsums[idx] = run;
    run += v[j];
  }
}

__global__ __launch_bounds__(256) void scan_add_kernel(
    int* __restrict__ out, const int* __restrict__ bsums, int n, int total) {
  int t = threadIdx.x;
  int base = blockIdx.x * SCAN_EPB + t * 4;
  int add = bsums[blockIdx.x];
#pragma unroll
  for (int j = 0; j < 4; ++j) {
    int idx = base + j;
    if (idx < n) out[idx] += add;
  }
  if (blockIdx.x == 0 && t == 0) out[n] = total;
}

// Atomic-free range-partitioned placement: slot = rp[dst] + rank[e].
// Range passes keep the scattered-write working set L2-local (R7 lesson).
__global__ __launch_bounds__(256) void place_range_kernel(
    const int* __restrict__ ev, const int* __restrict__ ec,
    const int* __restrict__ rp_v, const int* __restrict__ rp_c,
    const int* __restrict__ rank_v, const int* __restrict__ rank_c,
    int* __restrict__ esrc_v, int* __restrict__ esrc_c, int n_edges,
    int vlo, int vhi, int clo, int chi) {
  int stride = gridDim.x * 256;
  for (int e = blockIdx.x * 256 + threadIdx.x; e < n_edges; e += stride) {
    int v = ev[e], c = ec[e];
    if (c >= clo && c < chi) esrc_c[rp_c[c] + rank_c[e]] = v;
    if (v >= vlo && v < vhi) esrc_v[rp_v[v] + rank_v[e]] = c;
  }
}

// ---------------- degree-bucket permutation ----------------
// Rows batched 16-per-wave iterate to the batch MAX degree; random batching
// wastes ~45-55% of gather iterations on masked lanes. Bucketing rows by
// degree makes batches degree-uniform. Output is arithmetic-invariant.
__global__ __launch_bounds__(256) void bucket_count_kernel(
    const int* __restrict__ deg, int* __restrict__ bcnt, int n) {
  __shared__ int lb[NBUCK];
  int t = threadIdx.x;
  if (t < NBUCK) lb[t] = 0;
  __syncthreads();
  int stride = gridDim.x * 256;
  for (int i = blockIdx.x * 256 + t; i < n; i += stride) {
    int b = deg[i]; b = b < NBUCK - 1 ? b : NBUCK - 1;
    atomicAdd(&lb[b], 1);
  }
  __syncthreads();
  if (t < NBUCK && lb[t] > 0) atomicAdd(&bcnt[t], lb[t]);
}

__global__ void bucket_scan_kernel(int* __restrict__ bv, int* __restrict__ bc) {
  if (threadIdx.x == 0) {
    int s = 0;
    for (int i = 0; i < NBUCK; ++i) { int t = bv[i]; bv[i] = s; s += t; }
  } else if (threadIdx.x == 1) {
    int s = 0;
    for (int i = 0; i < NBUCK; ++i) { int t = bc[i]; bc[i] = s; s += t; }
  }
}

// Wave-aggregated cursor placement: one atomic per (wave, distinct bucket).
__global__ __launch_bounds__(256) void bucket_place_kernel(
    const int* __restrict__ deg, int* __restrict__ cursor,
    int* __restrict__ perm, int n) {
  int i = blockIdx.x * 256 + threadIdx.x;
  bool valid = i < n;
  int b = -1;
  if (valid) { b = deg[i]; b = b < NBUCK - 1 ? b : NBUCK - 1; }
  int lane = threadIdx.x & 63;
  unsigned long long lanebit = 1ull << lane;
  int slot = 0;
  bool done = !valid;
  for (;;) {
    unsigned long long todo = __ballot(!done);
    if (todo == 0) break;
    int leader = __ffsll((long long)todo) - 1;
    int lb = __shfl(b, leader, 64);
    bool mine = !done && (b == lb);
    unsigned long long same = __ballot(mine);
    if (mine) {
      int base = 0;
      if (lane == leader) base = atomicAdd(&cursor[lb], __popcll(same));
      base = __shfl(base, leader, 64);
      slot = base + __popcll(same & (lanebit - 1));
      done = true;
    }
  }
  if (valid) perm[slot] = i;
}

// ---------------- MFMA fused aggregate + linear + tanh (+ optional readout) ----------------
// 16 perm-consecutive (degree-uniform) dest rows per wave. Gather lands in MFMA
// A-operand layout; matvec = 8 x v_mfma_f32_16x16x32_f16 (C/D: col=lane&15,
// row=(lane>>4)*4+reg, m89-verified).
template<bool RO>
__global__ __launch_bounds__(256, 4) void fused_mfma_kernel(
    __half* __restrict__ hdst, const __half* __restrict__ hsrc,
    const int* __restrict__ rp, const int* __restrict__ esrc,
    const int* __restrict__ perm,
    const float* __restrict__ W, const float* __restrict__ b,
    const float* __restrict__ Wro, const float* __restrict__ bro,
    float* __restrict__ scores, int n_rows) {
  int t = threadIdx.x;
  int wave = t >> 6, lane = t & 63;
  int mm = lane & 15;   // dest-row slot within the 16-row batch
  int fb = lane >> 4;   // feature-block 0..3

  h8 Bf[4][2];
  float bvt[4], wrot[4];
#pragma unroll
  for (int tt = 0; tt < 4; ++tt) {
#pragma unroll
    for (int s = 0; s < 2; ++s) {
      const float* wp = W + (size_t)(16 * tt + mm) * 64 + 32 * s + 8 * fb;
      Bf[tt][s] = cvt8(*(const float4*)wp, *(const float4*)(wp + 4));
    }
    bvt[tt] = b[16 * tt + mm];
    wrot[tt] = RO ? Wro[16 * tt + mm] : 0.0f;
  }
  float brov = RO ? bro[0] : 0.0f;

  const float4* rows4 = (const float4*)hsrc;  // 8 float4 per 64-half row
  const h8 zh = h8zero();

  int stride16 = gridDim.x * WPB * 16;
  for (int rowb = (blockIdx.x * WPB + wave) * 16; rowb < n_rows; rowb += stride16) {
    int sidx = rowb + mm;
    int mc = perm[(sidx < n_rows) ? sidx : n_rows - 1];
    int p = rp[mc], end = rp[mc + 1];
    float degf = (float)(end - p);

    h8 a0 = zh, a1 = zh;
    while (__any(p < end)) {
      bool va = p < end;
      bool vb = p + 1 < end;
      int ia = va ? p : 0;
      int ib = vb ? (p + 1) : 0;
      int sa = esrc[ia];
      int sb = esrc[ib];
      float4 qa0 = rows4[(size_t)sa * 8 + fb];
      float4 qa1 = rows4[(size_t)sa * 8 + 4 + fb];
      float4 qb0 = rows4[(size_t)sb * 8 + fb];
      float4 qb1 = rows4[(size_t)sb * 8 + 4 + fb];
      a0 += va ? __builtin_bit_cast(h8, qa0) : zh;
      a1 += va ? __builtin_bit_cast(h8, qa1) : zh;
      a0 += vb ? __builtin_bit_cast(h8, qb0) : zh;
      a1 += vb ? __builtin_bit_cast(h8, qb1) : zh;
      p += 2;
    }

    // D[16x64] = A @ W^T : 4 n-tiles x 2 K-steps
    f32x4 d[4];
#pragma unroll
    for (int tt = 0; tt < 4; ++tt) {
      f32x4 dz; dz[0] = 0.f; dz[1] = 0.f; dz[2] = 0.f; dz[3] = 0.f;
      d[tt] = __builtin_amdgcn_mfma_f32_16x16x32_f16(a0, Bf[tt][0], dz, 0, 0, 0);
      d[tt] = __builtin_amdgcn_mfma_f32_16x16x32_f16(a1, Bf[tt][1], d[tt], 0, 0, 0);
    }

    // epilogue: lane l, reg i, tile t -> batch slot rowb+4*fb+i, col 16t+mm
#pragma unroll
    for (int i = 0; i < 4; ++i) {
      float deg_i = __shfl(degf, fb * 4 + i, 64);
      int bslot = rowb + fb * 4 + i;
      bool ok = bslot < n_rows;
      int grow = perm[ok ? bslot : n_rows - 1];
      float pr = 0.0f;
#pragma unroll
      for (int tt = 0; tt < 4; ++tt) {
        size_t addr = (size_t)grow * 64 + 16 * tt + mm;
        float hold = ok ? __half2float(hdst[addr]) : 0.0f;
        float hv = tanhf(hold + bvt[tt] * deg_i + d[tt][i]);
        if (RO) {
          pr += hv * wrot[tt];
        } else {
          if (ok) hdst[addr] = __float2half(hv);
        }
      }
      if (RO) {
        pr += __shfl_xor(pr, 1, 64);
        pr += __shfl_xor(pr, 2, 64);
        pr += __shfl_xor(pr, 4, 64);
        pr += __shfl_xor(pr, 8, 64);
        if (mm == 0 && ok) scores[grow] = pr + brov;
      }
    }
  }
}

// Capped persistent grids (R9: full grids replicate preambles, 2.3x regression).
static inline int rowgrid(int n) {
  int want = (n + WPB - 1) / WPB;
  return want < 2048 ? want : 2048;
}
static inline int rowgrid16(int n) {
  int want = (n + WPB * 16 - 1) / (WPB * 16);
  return want < 2048 ? want : 2048;
}

extern "C" void kernel_launch(void* const* d_in, const int* in_sizes, int n_in,
                              void* d_out, int out_size, void* d_ws, size_t ws_size,
                              hipStream_t stream) {
  const float* vf    = (const float*)d_in[0];
  const float* cf    = (const float*)d_in[1];
  const int*   ev    = (const int*)d_in[2];
  const int*   ec    = (const int*)d_in[3];
  const float* W_ve1 = (const float*)d_in[4];
  const float* b_ve1 = (const float*)d_in[5];
  const float* W_ve2 = (const float*)d_in[6];
  const float* b_ve2 = (const float*)d_in[7];
  const float* W_ce1 = (const float*)d_in[8];
  const float* b_ce1 = (const float*)d_in[9];
  const float* W_ce2 = (const float*)d_in[10];
  const float* b_ce2 = (const float*)d_in[11];
  const float* W_v2c = (const float*)d_in[12];
  const float* b_v2c = (const float*)d_in[13];
  const float* W_c2v = (const float*)d_in[14];
  const float* b_c2v = (const float*)d_in[15];
  const float* W_ro  = (const float*)d_in[16];
  const float* b_ro  = (const float*)d_in[17];

  const int n_vars  = in_sizes[0] / 7;
  const int n_cons  = in_sizes[1] / 5;
  const int n_edges = in_sizes[2];
  const int R       = in_sizes[12] / (64 * 64);

  // Workspace ~51.6 MB (budget ~55 MB — R13 overflow lesson).
  char* p = (char*)d_ws;
  __half* h_var = (__half*)p; p += (size_t)n_vars * 64 * 2;   // 25.6 MB
  __half* h_con = (__half*)p; p += (size_t)n_cons * 64 * 2;   // 12.8 MB
  int*   rp_v   = (int*)p;   p += (size_t)(n_vars + 1) * 4;
  int*   rp_c   = (int*)p;   p += (size_t)(n_cons + 1) * 4;
  int*   deg_v  = (int*)p;   p += (size_t)n_vars * 4;
  int*   deg_c  = (int*)p;   p += (size_t)n_cons * 4;
  int*   esrc_v = (int*)p;   p += (size_t)n_edges * 4;
  int*   esrc_c = (int*)p;   p += (size_t)n_edges * 4;
  int*   perm_v = (int*)p;   p += (size_t)n_vars * 4;
  int*   perm_c = (int*)p;   p += (size_t)n_cons * 4;
  int*   bsums  = (int*)p;   p += 1024 * 4;
  int*   bcnt_v = (int*)p;   p += NBUCK * 4;
  int*   bcnt_c = (int*)p;   p += NBUCK * 4;
  // rank arrays ALIAS h_var (dead after placement; encoder writes h_var later).
  int*   rank_v = (int*)h_var;
  int*   rank_c = (int*)h_var + n_edges;

  const int nb_v = (n_vars + SCAN_EPB - 1) / SCAN_EPB;
  const int nb_c = (n_cons + SCAN_EPB - 1) / SCAN_EPB;

  hipMemsetAsync(deg_v, 0, (size_t)n_vars * 4, stream);
  hipMemsetAsync(deg_c, 0, (size_t)n_cons * 4, stream);
  hipMemsetAsync(bcnt_v, 0, NBUCK * 4, stream);
  hipMemsetAsync(bcnt_c, 0, NBUCK * 4, stream);
  hist_rank_kernel<<<(n_edges + 255) / 256, 256, 0, stream>>>(
      ev, ec, deg_v, deg_c, rank_v, rank_c, n_edges);

  scan_blocks_kernel<<<nb_v, 256, 0, stream>>>(deg_v, rp_v, bsums, n_vars);
  scan_sums_kernel<<<1, 256, 0, stream>>>(bsums, nb_v);
  scan_add_kernel<<<nb_v, 256, 0, stream>>>(rp_v, bsums, n_vars, n_edges);
  scan_blocks_kernel<<<nb_c, 256, 0, stream>>>(deg_c, rp_c, bsums, n_cons);
  scan_sums_kernel<<<1, 256, 0, stream>>>(bsums, nb_c);
  scan_add_kernel<<<nb_c, 256, 0, stream>>>(rp_c, bsums, n_cons, n_edges);

  {
    const int vrng = (n_vars + PLACE_NB - 1) / PLACE_NB;
    const int crng = (n_cons + PLACE_NB - 1) / PLACE_NB;
    for (int bpass = 0; bpass < PLACE_NB; ++bpass) {
      int vlo = bpass * vrng, vhi = vlo + vrng;
      int clo = bpass * crng, chi = clo + crng;
      place_range_kernel<<<1024, 256, 0, stream>>>(
          ev, ec, rp_v, rp_c, rank_v, rank_c, esrc_v, esrc_c, n_edges,
          vlo, vhi, clo, chi);
    }
  }

  // degree-bucket permutations (arithmetic-invariant batching aid)
  bucket_count_kernel<<<256, 256, 0, stream>>>(deg_v, bcnt_v, n_vars);
  bucket_count_kernel<<<256, 256, 0, stream>>>(deg_c, bcnt_c, n_cons);
  bucket_scan_kernel<<<1, 64, 0, stream>>>(bcnt_v, bcnt_c);
  bucket_place_kernel<<<(n_vars + 255) / 256, 256, 0, stream>>>(
      deg_v, bcnt_v, perm_v, n_vars);
  bucket_place_kernel<<<(n_cons + 255) / 256, 256, 0, stream>>>(
      deg_c, bcnt_c, perm_c, n_cons);

  // encoders overwrite h_var (rank arrays dead by now)
  encoder_kernel<7><<<rowgrid(n_vars), 256, 0, stream>>>(
      vf, W_ve1, b_ve1, W_ve2, b_ve2, h_var, n_vars);
  encoder_kernel<5><<<rowgrid(n_cons), 256, 0, stream>>>(
      cf, W_ce1, b_ce1, W_ce2, b_ce2, h_con, n_cons);

  for (int r = 0; r < R; ++r) {
    fused_mfma_kernel<false><<<rowgrid16(n_cons), 256, 0, stream>>>(
        h_con, h_var, rp_c, esrc_c, perm_c,
        W_v2c + (size_t)r * 64 * 64, b_v2c + (size_t)r * 64,
        nullptr, nullptr, nullptr, n_cons);
    if (r == R - 1) {
      fused_mfma_kernel<true><<<rowgrid16(n_vars), 256, 0, stream>>>(
          h_var, h_con, rp_v, esrc_v, perm_v,
          W_c2v + (size_t)r * 64 * 64, b_c2v + (size_t)r * 64,
          W_ro, b_ro, (float*)d_out, n_vars);
    } else {
      fused_mfma_kernel<false><<<rowgrid16(n_vars), 256, 0, stream>>>(
          h_var, h_con, rp_v, esrc_v, perm_v,
          W_c2v + (size_t)r * 64 * 64, b_c2v + (size_t)r * 64,
          nullptr, nullptr, nullptr, n_vars);
    }
  }
}

// Round 16
// 614.255 us; speedup vs baseline: 1.9123x; 1.9123x over previous
//
#include <hip/hip_runtime.h>
#include <hip/hip_bf16.h>
#include <hip/hip_fp16.h>

#define WPB 4          // waves per block (256 threads)
#define SCAN_EPB 1024  // elements per scan block (256 thr x 4)
#define PLACE_NB 4     // sequential destination-range passes for CSR placement
#define NBUCK 32       // degree buckets for row batching

typedef _Float16 h8 __attribute__((ext_vector_type(8)));
typedef float f32x4 __attribute__((ext_vector_type(4)));

__device__ __forceinline__ float bcast(float v, int i) {
  return __builtin_bit_cast(float, __builtin_amdgcn_readlane(__builtin_bit_cast(int, v), i));
}
__device__ __forceinline__ h8 h8zero() {
  h8 r;
#pragma unroll
  for (int j = 0; j < 8; ++j) r[j] = (_Float16)0;
  return r;
}
__device__ __forceinline__ h8 cvt8(float4 a, float4 b) {
  h8 r;
  r[0] = (_Float16)a.x; r[1] = (_Float16)a.y; r[2] = (_Float16)a.z; r[3] = (_Float16)a.w;
  r[4] = (_Float16)b.x; r[5] = (_Float16)b.y; r[6] = (_Float16)b.z; r[7] = (_Float16)b.w;
  return r;
}

// ---------------- encoders ----------------
// out = tanh(x @ W1^T + b1) @ W2^T + b2. One row per wave; W in VGPRs; f16 output.
// Persistent capped grid (R9: full grids replicate the W->VGPR preamble, 2.3x slower).
template<int IN_F>
__global__ __launch_bounds__(256, 4) void encoder_kernel(
    const float* __restrict__ x,
    const float* __restrict__ W1, const float* __restrict__ b1,
    const float* __restrict__ W2, const float* __restrict__ b2,
    __half* __restrict__ out, int n_rows) {
  int t = threadIdx.x;
  int wave = t >> 6, lane = t & 63;

  float w1reg[IN_F];
#pragma unroll
  for (int j = 0; j < IN_F; ++j) w1reg[j] = W1[lane * IN_F + j];
  float w2reg[64];
  const float4* W24 = (const float4*)(W2 + (size_t)lane * 64);
#pragma unroll
  for (int i = 0; i < 16; ++i) {
    float4 w = W24[i];
    w2reg[4 * i] = w.x; w2reg[4 * i + 1] = w.y;
    w2reg[4 * i + 2] = w.z; w2reg[4 * i + 3] = w.w;
  }
  float b1v = b1[lane], b2v = b2[lane];

  int stride = gridDim.x * WPB;
  for (int row = blockIdx.x * WPB + wave; row < n_rows; row += stride) {
    float xl = 0.0f;
    if (lane < IN_F) xl = x[(size_t)row * IN_F + lane];
    float h = b1v;
#pragma unroll
    for (int j = 0; j < IN_F; ++j) h += w1reg[j] * bcast(xl, j);
    float hid = tanhf(h);

    float o0 = b2v, o1 = 0.f, o2 = 0.f, o3 = 0.f;
#pragma unroll
    for (int i = 0; i < 64; i += 4) {
      o0 += w2reg[i]     * bcast(hid, i);
      o1 += w2reg[i + 1] * bcast(hid, i + 1);
      o2 += w2reg[i + 2] * bcast(hid, i + 2);
      o3 += w2reg[i + 3] * bcast(hid, i + 3);
    }
    out[(size_t)row * 64 + lane] = __float2half((o0 + o1) + (o2 + o3));
  }
}

// ---------------- CSR build ----------------
// The single scattered-atomic pass (transaction-floor ~26 G/s) also emits
// per-edge ranks, making placement atomic-free.
__global__ __launch_bounds__(256) void hist_rank_kernel(
    const int* __restrict__ ev, const int* __restrict__ ec,
    int* __restrict__ deg_v, int* __restrict__ deg_c,
    int* __restrict__ rank_v, int* __restrict__ rank_c, int n_edges) {
  int e = blockIdx.x * 256 + threadIdx.x;
  if (e >= n_edges) return;
  rank_v[e] = atomicAdd(&deg_v[ev[e]], 1);
  rank_c[e] = atomicAdd(&deg_c[ec[e]], 1);
}

__global__ __launch_bounds__(256) void scan_blocks_kernel(
    const int* __restrict__ in, int* __restrict__ out,
    int* __restrict__ bsums, int n) {
  __shared__ int s[256];
  int t = threadIdx.x;
  int base = blockIdx.x * SCAN_EPB + t * 4;
  int v[4]; int local = 0;
#pragma unroll
  for (int j = 0; j < 4; ++j) {
    int idx = base + j;
    v[j] = (idx < n) ? in[idx] : 0;
    local += v[j];
  }
  s[t] = local;
  __syncthreads();
  for (int off = 1; off < 256; off <<= 1) {
    int val = (t >= off) ? s[t - off] : 0;
    __syncthreads();
    s[t] += val;
    __syncthreads();
  }
  int run = s[t] - local;
#pragma unroll
  for (int j = 0; j < 4; ++j) {
    int idx = base + j;
    if (idx < n) out[idx] = run;
    run += v[j];
  }
  if (t == 255) bsums[blockIdx.x] = s[255];
}

__global__ __launch_bounds__(256) void scan_sums_kernel(int* __restrict__ bsums, int nb) {
  __shared__ int s[256];
  int t = threadIdx.x;
  int base = t * 4;
  int v[4]; int local = 0;
#pragma unroll
  for (int j = 0; j < 4; ++j) {
    int idx = base + j;
    v[j] = (idx < nb) ? bsums[idx] : 0;
    local += v[j];
  }
  s[t] = local;
  __syncthreads();
  for (int off = 1; off < 256; off <<= 1) {
    int val = (t >= off) ? s[t - off] : 0;
    __syncthreads();
    s[t] += val;
    __syncthreads();
  }
  int run = s[t] - local;
#pragma unroll
  for (int j = 0; j < 4; ++j) {
    int idx = base + j;
    if (idx < nb) bsums[idx] = run;
    run += v[j];
  }
}

__global__ __launch_bounds__(256) void scan_add_kernel(
    int* __restrict__ out, const int* __restrict__ bsums, int n, int total) {
  int t = threadIdx.x;
  int base = blockIdx.x * SCAN_EPB + t * 4;
  int add = bsums[blockIdx.x];
#pragma unroll
  for (int j = 0; j < 4; ++j) {
    int idx = base + j;
    if (idx < n) out[idx] += add;
  }
  if (blockIdx.x == 0 && t == 0) out[n] = total;
}

// Atomic-free range-partitioned placement: slot = rp[dst] + rank[e].
// Range passes keep the scattered-write working set L2-local (R7 lesson).
__global__ __launch_bounds__(256) void place_range_kernel(
    const int* __restrict__ ev, const int* __restrict__ ec,
    const int* __restrict__ rp_v, const int* __restrict__ rp_c,
    const int* __restrict__ rank_v, const int* __restrict__ rank_c,
    int* __restrict__ esrc_v, int* __restrict__ esrc_c, int n_edges,
    int vlo, int vhi, int clo, int chi) {
  int stride = gridDim.x * 256;
  for (int e = blockIdx.x * 256 + threadIdx.x; e < n_edges; e += stride) {
    int v = ev[e], c = ec[e];
    if (c >= clo && c < chi) esrc_c[rp_c[c] + rank_c[e]] = v;
    if (v >= vlo && v < vhi) esrc_v[rp_v[v] + rank_v[e]] = c;
  }
}

// ---------------- degree-bucket permutation ----------------
// Degree-uniform 16-row batches eliminate masked gather waste in the fused
// kernels (R15: confirmed benefit). Permutation build must avoid concentrated
// atomics (R15: 32 shared cursors = 2 cache lines -> 401 us serialization).
__global__ __launch_bounds__(256) void bucket_count_kernel(
    const int* __restrict__ deg, int* __restrict__ bcnt, int n) {
  __shared__ int lb[NBUCK];
  int t = threadIdx.x;
  if (t < NBUCK) lb[t] = 0;
  __syncthreads();
  int stride = gridDim.x * 256;
  for (int i = blockIdx.x * 256 + t; i < n; i += stride) {
    int b = deg[i]; b = b < NBUCK - 1 ? b : NBUCK - 1;
    atomicAdd(&lb[b], 1);
  }
  __syncthreads();
  if (t < NBUCK && lb[t] > 0) atomicAdd(&bcnt[t], lb[t]);
}

__global__ void bucket_scan_kernel(int* __restrict__ bv, int* __restrict__ bc) {
  if (threadIdx.x == 0) {
    int s = 0;
    for (int i = 0; i < NBUCK; ++i) { int t = bv[i]; bv[i] = s; s += t; }
  } else if (threadIdx.x == 1) {
    int s = 0;
    for (int i = 0; i < NBUCK; ++i) { int t = bc[i]; bc[i] = s; s += t; }
  }
}

// Hierarchical placement: LDS-atomic local ranks + one global atomic per
// (block, bucket) range reservation (~6K spread atomics total, no hot lines).
__global__ __launch_bounds__(256) void bucket_place_kernel(
    const int* __restrict__ deg, int* __restrict__ cursor,
    int* __restrict__ perm, int n) {
  __shared__ int lhist[NBUCK];
  __shared__ int lbase[NBUCK];
  int t = threadIdx.x;
  if (t < NBUCK) lhist[t] = 0;
  __syncthreads();

  int base = blockIdx.x * SCAN_EPB;  // 1024 elements per block
  int b[4], lrank[4];
#pragma unroll
  for (int j = 0; j < 4; ++j) {
    int idx = base + t * 4 + j;
    if (idx < n) {
      int d = deg[idx]; d = d < NBUCK - 1 ? d : NBUCK - 1;
      b[j] = d;
      lrank[j] = atomicAdd(&lhist[d], 1);   // LDS atomic: local rank
    } else b[j] = -1;
  }
  __syncthreads();
  if (t < NBUCK && lhist[t] > 0) lbase[t] = atomicAdd(&cursor[t], lhist[t]);
  __syncthreads();
#pragma unroll
  for (int j = 0; j < 4; ++j) {
    int idx = base + t * 4 + j;
    if (idx < n) perm[lbase[b[j]] + lrank[j]] = idx;
  }
}

// ---------------- MFMA fused aggregate + linear + tanh (+ optional readout) ----------------
// 16 perm-consecutive (degree-uniform) dest rows per wave. Gather lands in MFMA
// A-operand layout; matvec = 8 x v_mfma_f32_16x16x32_f16 (C/D: col=lane&15,
// row=(lane>>4)*4+reg, m89-verified).
template<bool RO>
__global__ __launch_bounds__(256, 4) void fused_mfma_kernel(
    __half* __restrict__ hdst, const __half* __restrict__ hsrc,
    const int* __restrict__ rp, const int* __restrict__ esrc,
    const int* __restrict__ perm,
    const float* __restrict__ W, const float* __restrict__ b,
    const float* __restrict__ Wro, const float* __restrict__ bro,
    float* __restrict__ scores, int n_rows) {
  int t = threadIdx.x;
  int wave = t >> 6, lane = t & 63;
  int mm = lane & 15;   // dest-row slot within the 16-row batch
  int fb = lane >> 4;   // feature-block 0..3

  h8 Bf[4][2];
  float bvt[4], wrot[4];
#pragma unroll
  for (int tt = 0; tt < 4; ++tt) {
#pragma unroll
    for (int s = 0; s < 2; ++s) {
      const float* wp = W + (size_t)(16 * tt + mm) * 64 + 32 * s + 8 * fb;
      Bf[tt][s] = cvt8(*(const float4*)wp, *(const float4*)(wp + 4));
    }
    bvt[tt] = b[16 * tt + mm];
    wrot[tt] = RO ? Wro[16 * tt + mm] : 0.0f;
  }
  float brov = RO ? bro[0] : 0.0f;

  const float4* rows4 = (const float4*)hsrc;  // 8 float4 per 64-half row
  const h8 zh = h8zero();

  int stride16 = gridDim.x * WPB * 16;
  for (int rowb = (blockIdx.x * WPB + wave) * 16; rowb < n_rows; rowb += stride16) {
    int sidx = rowb + mm;
    int mc = perm[(sidx < n_rows) ? sidx : n_rows - 1];
    int p = rp[mc], end = rp[mc + 1];
    float degf = (float)(end - p);

    h8 a0 = zh, a1 = zh;
    while (__any(p < end)) {
      bool va = p < end;
      bool vb = p + 1 < end;
      int ia = va ? p : 0;
      int ib = vb ? (p + 1) : 0;
      int sa = esrc[ia];
      int sb = esrc[ib];
      float4 qa0 = rows4[(size_t)sa * 8 + fb];
      float4 qa1 = rows4[(size_t)sa * 8 + 4 + fb];
      float4 qb0 = rows4[(size_t)sb * 8 + fb];
      float4 qb1 = rows4[(size_t)sb * 8 + 4 + fb];
      a0 += va ? __builtin_bit_cast(h8, qa0) : zh;
      a1 += va ? __builtin_bit_cast(h8, qa1) : zh;
      a0 += vb ? __builtin_bit_cast(h8, qb0) : zh;
      a1 += vb ? __builtin_bit_cast(h8, qb1) : zh;
      p += 2;
    }

    // D[16x64] = A @ W^T : 4 n-tiles x 2 K-steps
    f32x4 d[4];
#pragma unroll
    for (int tt = 0; tt < 4; ++tt) {
      f32x4 dz; dz[0] = 0.f; dz[1] = 0.f; dz[2] = 0.f; dz[3] = 0.f;
      d[tt] = __builtin_amdgcn_mfma_f32_16x16x32_f16(a0, Bf[tt][0], dz, 0, 0, 0);
      d[tt] = __builtin_amdgcn_mfma_f32_16x16x32_f16(a1, Bf[tt][1], d[tt], 0, 0, 0);
    }

    // epilogue: lane l, reg i, tile t -> batch slot rowb+4*fb+i, col 16t+mm
#pragma unroll
    for (int i = 0; i < 4; ++i) {
      float deg_i = __shfl(degf, fb * 4 + i, 64);
      int bslot = rowb + fb * 4 + i;
      bool ok = bslot < n_rows;
      int grow = perm[ok ? bslot : n_rows - 1];
      float pr = 0.0f;
#pragma unroll
      for (int tt = 0; tt < 4; ++tt) {
        size_t addr = (size_t)grow * 64 + 16 * tt + mm;
        float hold = ok ? __half2float(hdst[addr]) : 0.0f;
        float hv = tanhf(hold + bvt[tt] * deg_i + d[tt][i]);
        if (RO) {
          pr += hv * wrot[tt];
        } else {
          if (ok) hdst[addr] = __float2half(hv);
        }
      }
      if (RO) {
        pr += __shfl_xor(pr, 1, 64);
        pr += __shfl_xor(pr, 2, 64);
        pr += __shfl_xor(pr, 4, 64);
        pr += __shfl_xor(pr, 8, 64);
        if (mm == 0 && ok) scores[grow] = pr + brov;
      }
    }
  }
}

// Capped persistent grids (R9: full grids replicate preambles, 2.3x regression).
static inline int rowgrid(int n) {
  int want = (n + WPB - 1) / WPB;
  return want < 2048 ? want : 2048;
}
static inline int rowgrid16(int n) {
  int want = (n + WPB * 16 - 1) / (WPB * 16);
  return want < 2048 ? want : 2048;
}

extern "C" void kernel_launch(void* const* d_in, const int* in_sizes, int n_in,
                              void* d_out, int out_size, void* d_ws, size_t ws_size,
                              hipStream_t stream) {
  const float* vf    = (const float*)d_in[0];
  const float* cf    = (const float*)d_in[1];
  const int*   ev    = (const int*)d_in[2];
  const int*   ec    = (const int*)d_in[3];
  const float* W_ve1 = (const float*)d_in[4];
  const float* b_ve1 = (const float*)d_in[5];
  const float* W_ve2 = (const float*)d_in[6];
  const float* b_ve2 = (const float*)d_in[7];
  const float* W_ce1 = (const float*)d_in[8];
  const float* b_ce1 = (const float*)d_in[9];
  const float* W_ce2 = (const float*)d_in[10];
  const float* b_ce2 = (const float*)d_in[11];
  const float* W_v2c = (const float*)d_in[12];
  const float* b_v2c = (const float*)d_in[13];
  const float* W_c2v = (const float*)d_in[14];
  const float* b_c2v = (const float*)d_in[15];
  const float* W_ro  = (const float*)d_in[16];
  const float* b_ro  = (const float*)d_in[17];

  const int n_vars  = in_sizes[0] / 7;
  const int n_cons  = in_sizes[1] / 5;
  const int n_edges = in_sizes[2];
  const int R       = in_sizes[12] / (64 * 64);

  // Workspace ~51.6 MB (budget ~55 MB — R13 overflow lesson).
  char* p = (char*)d_ws;
  __half* h_var = (__half*)p; p += (size_t)n_vars * 64 * 2;   // 25.6 MB
  __half* h_con = (__half*)p; p += (size_t)n_cons * 64 * 2;   // 12.8 MB
  int*   rp_v   = (int*)p;   p += (size_t)(n_vars + 1) * 4;
  int*   rp_c   = (int*)p;   p += (size_t)(n_cons + 1) * 4;
  int*   deg_v  = (int*)p;   p += (size_t)n_vars * 4;
  int*   deg_c  = (int*)p;   p += (size_t)n_cons * 4;
  int*   esrc_v = (int*)p;   p += (size_t)n_edges * 4;
  int*   esrc_c = (int*)p;   p += (size_t)n_edges * 4;
  int*   perm_v = (int*)p;   p += (size_t)n_vars * 4;
  int*   perm_c = (int*)p;   p += (size_t)n_cons * 4;
  int*   bsums  = (int*)p;   p += 1024 * 4;
  int*   bcnt_v = (int*)p;   p += NBUCK * 4;
  int*   bcnt_c = (int*)p;   p += NBUCK * 4;
  // rank arrays ALIAS h_var (dead after placement; encoder writes h_var later).
  int*   rank_v = (int*)h_var;
  int*   rank_c = (int*)h_var + n_edges;

  const int nb_v = (n_vars + SCAN_EPB - 1) / SCAN_EPB;
  const int nb_c = (n_cons + SCAN_EPB - 1) / SCAN_EPB;

  hipMemsetAsync(deg_v, 0, (size_t)n_vars * 4, stream);
  hipMemsetAsync(deg_c, 0, (size_t)n_cons * 4, stream);
  hipMemsetAsync(bcnt_v, 0, NBUCK * 4, stream);
  hipMemsetAsync(bcnt_c, 0, NBUCK * 4, stream);
  hist_rank_kernel<<<(n_edges + 255) / 256, 256, 0, stream>>>(
      ev, ec, deg_v, deg_c, rank_v, rank_c, n_edges);

  scan_blocks_kernel<<<nb_v, 256, 0, stream>>>(deg_v, rp_v, bsums, n_vars);
  scan_sums_kernel<<<1, 256, 0, stream>>>(bsums, nb_v);
  scan_add_kernel<<<nb_v, 256, 0, stream>>>(rp_v, bsums, n_vars, n_edges);
  scan_blocks_kernel<<<nb_c, 256, 0, stream>>>(deg_c, rp_c, bsums, n_cons);
  scan_sums_kernel<<<1, 256, 0, stream>>>(bsums, nb_c);
  scan_add_kernel<<<nb_c, 256, 0, stream>>>(rp_c, bsums, n_cons, n_edges);

  {
    const int vrng = (n_vars + PLACE_NB - 1) / PLACE_NB;
    const int crng = (n_cons + PLACE_NB - 1) / PLACE_NB;
    for (int bpass = 0; bpass < PLACE_NB; ++bpass) {
      int vlo = bpass * vrng, vhi = vlo + vrng;
      int clo = bpass * crng, chi = clo + crng;
      place_range_kernel<<<1024, 256, 0, stream>>>(
          ev, ec, rp_v, rp_c, rank_v, rank_c, esrc_v, esrc_c, n_edges,
          vlo, vhi, clo, chi);
    }
  }

  // degree-bucket permutations (arithmetic-invariant batching aid)
  bucket_count_kernel<<<256, 256, 0, stream>>>(deg_v, bcnt_v, n_vars);
  bucket_count_kernel<<<256, 256, 0, stream>>>(deg_c, bcnt_c, n_cons);
  bucket_scan_kernel<<<1, 64, 0, stream>>>(bcnt_v, bcnt_c);
  bucket_place_kernel<<<nb_v, 256, 0, stream>>>(deg_v, bcnt_v, perm_v, n_vars);
  bucket_place_kernel<<<nb_c, 256, 0, stream>>>(deg_c, bcnt_c, perm_c, n_cons);

  // encoders overwrite h_var (rank arrays dead by now)
  encoder_kernel<7><<<rowgrid(n_vars), 256, 0, stream>>>(
      vf, W_ve1, b_ve1, W_ve2, b_ve2, h_var, n_vars);
  encoder_kernel<5><<<rowgrid(n_cons), 256, 0, stream>>>(
      cf, W_ce1, b_ce1, W_ce2, b_ce2, h_con, n_cons);

  for (int r = 0; r < R; ++r) {
    fused_mfma_kernel<false><<<rowgrid16(n_cons), 256, 0, stream>>>(
        h_con, h_var, rp_c, esrc_c, perm_c,
        W_v2c + (size_t)r * 64 * 64, b_v2c + (size_t)r * 64,
        nullptr, nullptr, nullptr, n_cons);
    if (r == R - 1) {
      fused_mfma_kernel<true><<<rowgrid16(n_vars), 256, 0, stream>>>(
          h_var, h_con, rp_v, esrc_v, perm_v,
          W_c2v + (size_t)r * 64 * 64, b_c2v + (size_t)r * 64,
          W_ro, b_ro, (float*)d_out, n_vars);
    } else {
      fused_mfma_kernel<false><<<rowgrid16(n_vars), 256, 0, stream>>>(
          h_var, h_con, rp_v, esrc_v, perm_v,
          W_c2v + (size_t)r * 64 * 64, b_c2v + (size_t)r * 64,
          nullptr, nullptr, nullptr, n_vars);
    }
  }
}

// Round 17
// 553.045 us; speedup vs baseline: 2.1239x; 1.1107x over previous
//
#include <hip/hip_runtime.h>
#include <hip/hip_bf16.h>
#include <hip/hip_fp16.h>

#define WPB 4          // waves per block (256 threads)
#define SCAN_EPB 1024  // elements per scan block (256 thr x 4)
#define PLACE_NB 4     // sequential destination-range passes for CSR placement

typedef _Float16 h8 __attribute__((ext_vector_type(8)));
typedef float f32x4 __attribute__((ext_vector_type(4)));

__device__ __forceinline__ float bcast(float v, int i) {
  return __builtin_bit_cast(float, __builtin_amdgcn_readlane(__builtin_bit_cast(int, v), i));
}
__device__ __forceinline__ h8 h8zero() {
  h8 r;
#pragma unroll
  for (int j = 0; j < 8; ++j) r[j] = (_Float16)0;
  return r;
}
__device__ __forceinline__ h8 cvt8(float4 a, float4 b) {
  h8 r;
  r[0] = (_Float16)a.x; r[1] = (_Float16)a.y; r[2] = (_Float16)a.z; r[3] = (_Float16)a.w;
  r[4] = (_Float16)b.x; r[5] = (_Float16)b.y; r[6] = (_Float16)b.z; r[7] = (_Float16)b.w;
  return r;
}

// ---------------- encoders ----------------
// out = tanh(x @ W1^T + b1) @ W2^T + b2. One row per wave; W in VGPRs; f16 output.
// Persistent capped grid (R9: full grids replicate the W->VGPR preamble, 2.3x slower).
template<int IN_F>
__global__ __launch_bounds__(256, 4) void encoder_kernel(
    const float* __restrict__ x,
    const float* __restrict__ W1, const float* __restrict__ b1,
    const float* __restrict__ W2, const float* __restrict__ b2,
    __half* __restrict__ out, int n_rows) {
  int t = threadIdx.x;
  int wave = t >> 6, lane = t & 63;

  float w1reg[IN_F];
#pragma unroll
  for (int j = 0; j < IN_F; ++j) w1reg[j] = W1[lane * IN_F + j];
  float w2reg[64];
  const float4* W24 = (const float4*)(W2 + (size_t)lane * 64);
#pragma unroll
  for (int i = 0; i < 16; ++i) {
    float4 w = W24[i];
    w2reg[4 * i] = w.x; w2reg[4 * i + 1] = w.y;
    w2reg[4 * i + 2] = w.z; w2reg[4 * i + 3] = w.w;
  }
  float b1v = b1[lane], b2v = b2[lane];

  int stride = gridDim.x * WPB;
  for (int row = blockIdx.x * WPB + wave; row < n_rows; row += stride) {
    float xl = 0.0f;
    if (lane < IN_F) xl = x[(size_t)row * IN_F + lane];
    float h = b1v;
#pragma unroll
    for (int j = 0; j < IN_F; ++j) h += w1reg[j] * bcast(xl, j);
    float hid = tanhf(h);

    float o0 = b2v, o1 = 0.f, o2 = 0.f, o3 = 0.f;
#pragma unroll
    for (int i = 0; i < 64; i += 4) {
      o0 += w2reg[i]     * bcast(hid, i);
      o1 += w2reg[i + 1] * bcast(hid, i + 1);
      o2 += w2reg[i + 2] * bcast(hid, i + 2);
      o3 += w2reg[i + 3] * bcast(hid, i + 3);
    }
    out[(size_t)row * 64 + lane] = __float2half((o0 + o1) + (o2 + o3));
  }
}

// ---------------- weight pre-conversion ----------------
// Convert R round-matrices (64x64 f32) into fragment-major f16: for round r,
// fragment f = tt*2+s, lane l: element j = W[r][16*tt + (l&15)][32*s + 8*(l>>4) + j].
// Fused waves then load their B-fragments as 8 coalesced dwordx4 (no cvts).
__global__ __launch_bounds__(256) void wcvt_kernel(
    const float* __restrict__ W, h8* __restrict__ Wh, int total) {  // total = R*512
  int tid = blockIdx.x * 256 + threadIdx.x;
  if (tid >= total) return;
  int l = tid & 63;
  int f = (tid >> 6) & 7;
  int r = tid >> 9;
  int tt = f >> 1, s = f & 1;
  const float* wp = W + (size_t)r * 4096 + (size_t)(16 * tt + (l & 15)) * 64
                    + 32 * s + 8 * (l >> 4);
  Wh[tid] = cvt8(*(const float4*)wp, *(const float4*)(wp + 4));
}

// ---------------- CSR build ----------------
// The single scattered-atomic pass (~24 cy/atomic/CU issue floor — R12 proved
// privatization can't move it) also emits per-edge ranks -> placement atomic-free.
__global__ __launch_bounds__(256) void hist_rank_kernel(
    const int* __restrict__ ev, const int* __restrict__ ec,
    int* __restrict__ deg_v, int* __restrict__ deg_c,
    int* __restrict__ rank_v, int* __restrict__ rank_c, int n_edges) {
  int e = blockIdx.x * 256 + threadIdx.x;
  if (e >= n_edges) return;
  rank_v[e] = atomicAdd(&deg_v[ev[e]], 1);
  rank_c[e] = atomicAdd(&deg_c[ec[e]], 1);
}

__global__ __launch_bounds__(256) void scan_blocks_kernel(
    const int* __restrict__ in, int* __restrict__ out,
    int* __restrict__ bsums, int n) {
  __shared__ int s[256];
  int t = threadIdx.x;
  int base = blockIdx.x * SCAN_EPB + t * 4;
  int v[4]; int local = 0;
#pragma unroll
  for (int j = 0; j < 4; ++j) {
    int idx = base + j;
    v[j] = (idx < n) ? in[idx] : 0;
    local += v[j];
  }
  s[t] = local;
  __syncthreads();
  for (int off = 1; off < 256; off <<= 1) {
    int val = (t >= off) ? s[t - off] : 0;
    __syncthreads();
    s[t] += val;
    __syncthreads();
  }
  int run = s[t] - local;
#pragma unroll
  for (int j = 0; j < 4; ++j) {
    int idx = base + j;
    if (idx < n) out[idx] = run;
    run += v[j];
  }
  if (t == 255) bsums[blockIdx.x] = s[255];
}

__global__ __launch_bounds__(256) void scan_sums_kernel(int* __restrict__ bsums, int nb) {
  __shared__ int s[256];
  int t = threadIdx.x;
  int base = t * 4;
  int v[4]; int local = 0;
#pragma unroll
  for (int j = 0; j < 4; ++j) {
    int idx = base + j;
    v[j] = (idx < nb) ? bsums[idx] : 0;
    local += v[j];
  }
  s[t] = local;
  __syncthreads();
  for (int off = 1; off < 256; off <<= 1) {
    int val = (t >= off) ? s[t - off] : 0;
    __syncthreads();
    s[t] += val;
    __syncthreads();
  }
  int run = s[t] - local;
#pragma unroll
  for (int j = 0; j < 4; ++j) {
    int idx = base + j;
    if (idx < nb) bsums[idx] = run;
    run += v[j];
  }
}

__global__ __launch_bounds__(256) void scan_add_kernel(
    int* __restrict__ out, const int* __restrict__ bsums, int n, int total) {
  int t = threadIdx.x;
  int base = blockIdx.x * SCAN_EPB + t * 4;
  int add = bsums[blockIdx.x];
#pragma unroll
  for (int j = 0; j < 4; ++j) {
    int idx = base + j;
    if (idx < n) out[idx] += add;
  }
  if (blockIdx.x == 0 && t == 0) out[n] = total;
}

// Atomic-free range-partitioned placement: slot = rp[dst] + rank[e].
// Range passes keep the scattered-write working set L2-local (R7 lesson).
__global__ __launch_bounds__(256) void place_range_kernel(
    const int* __restrict__ ev, const int* __restrict__ ec,
    const int* __restrict__ rp_v, const int* __restrict__ rp_c,
    const int* __restrict__ rank_v, const int* __restrict__ rank_c,
    int* __restrict__ esrc_v, int* __restrict__ esrc_c, int n_edges,
    int vlo, int vhi, int clo, int chi) {
  int stride = gridDim.x * 256;
  for (int e = blockIdx.x * 256 + threadIdx.x; e < n_edges; e += stride) {
    int v = ev[e], c = ec[e];
    if (c >= clo && c < chi) esrc_c[rp_c[c] + rank_c[e]] = v;
    if (v >= vlo && v < vhi) esrc_v[rp_v[v] + rank_v[e]] = c;
  }
}

// ---------------- MFMA fused aggregate + linear + tanh (+ optional readout) ----------------
// 16 consecutive dest rows per wave. Gather in MFMA A-operand layout, 4 edges
// per iteration (12 loads in flight). B-fragments loaded pre-converted (8
// coalesced dwordx4, no cvt). C/D: col=lane&15, row=(lane>>4)*4+reg (m89).
template<bool RO>
__global__ __launch_bounds__(256, 4) void fused_mfma_kernel(
    __half* __restrict__ hdst, const __half* __restrict__ hsrc,
    const int* __restrict__ rp, const int* __restrict__ esrc,
    const h8* __restrict__ Wh, const float* __restrict__ b,
    const float* __restrict__ Wro, const float* __restrict__ bro,
    float* __restrict__ scores, int n_rows) {
  int t = threadIdx.x;
  int wave = t >> 6, lane = t & 63;
  int mm = lane & 15;   // dest-row slot within the 16-row batch
  int fb = lane >> 4;   // feature-block 0..3

  h8 Bf[4][2];
  float bvt[4], wrot[4];
#pragma unroll
  for (int tt = 0; tt < 4; ++tt) {
#pragma unroll
    for (int s = 0; s < 2; ++s) Bf[tt][s] = Wh[(tt * 2 + s) * 64 + lane];
    bvt[tt] = b[16 * tt + mm];
    wrot[tt] = RO ? Wro[16 * tt + mm] : 0.0f;
  }
  float brov = RO ? bro[0] : 0.0f;

  const float4* rows4 = (const float4*)hsrc;  // 8 float4 per 64-half row
  const h8 zh = h8zero();

  int stride16 = gridDim.x * WPB * 16;
  for (int rowb = (blockIdx.x * WPB + wave) * 16; rowb < n_rows; rowb += stride16) {
    int mrow = rowb + mm;
    int mc = (mrow < n_rows) ? mrow : n_rows - 1;
    int p = rp[mc], end = rp[mc + 1];
    float degf = (float)(end - p);

    h8 a0 = zh, a1 = zh;
    while (__any(p < end)) {
      bool v0 = p < end, v1 = p + 1 < end, v2 = p + 2 < end, v3 = p + 3 < end;
      int i0 = v0 ? p : 0;
      int i1 = v1 ? p + 1 : 0;
      int i2 = v2 ? p + 2 : 0;
      int i3 = v3 ? p + 3 : 0;
      int s0 = esrc[i0];
      int s1 = esrc[i1];
      int s2 = esrc[i2];
      int s3 = esrc[i3];
      float4 q0a = rows4[(size_t)s0 * 8 + fb];
      float4 q0b = rows4[(size_t)s0 * 8 + 4 + fb];
      float4 q1a = rows4[(size_t)s1 * 8 + fb];
      float4 q1b = rows4[(size_t)s1 * 8 + 4 + fb];
      float4 q2a = rows4[(size_t)s2 * 8 + fb];
      float4 q2b = rows4[(size_t)s2 * 8 + 4 + fb];
      float4 q3a = rows4[(size_t)s3 * 8 + fb];
      float4 q3b = rows4[(size_t)s3 * 8 + 4 + fb];
      a0 += v0 ? __builtin_bit_cast(h8, q0a) : zh;
      a1 += v0 ? __builtin_bit_cast(h8, q0b) : zh;
      a0 += v1 ? __builtin_bit_cast(h8, q1a) : zh;
      a1 += v1 ? __builtin_bit_cast(h8, q1b) : zh;
      a0 += v2 ? __builtin_bit_cast(h8, q2a) : zh;
      a1 += v2 ? __builtin_bit_cast(h8, q2b) : zh;
      a0 += v3 ? __builtin_bit_cast(h8, q3a) : zh;
      a1 += v3 ? __builtin_bit_cast(h8, q3b) : zh;
      p += 4;
    }

    // D[16x64] = A @ W^T : 4 n-tiles x 2 K-steps
    f32x4 d[4];
#pragma unroll
    for (int tt = 0; tt < 4; ++tt) {
      f32x4 dz; dz[0] = 0.f; dz[1] = 0.f; dz[2] = 0.f; dz[3] = 0.f;
      d[tt] = __builtin_amdgcn_mfma_f32_16x16x32_f16(a0, Bf[tt][0], dz, 0, 0, 0);
      d[tt] = __builtin_amdgcn_mfma_f32_16x16x32_f16(a1, Bf[tt][1], d[tt], 0, 0, 0);
    }

    // epilogue: lane l, reg i, tile t -> row rowb + 4*fb + i, col 16t + mm
#pragma unroll
    for (int i = 0; i < 4; ++i) {
      float deg_i = __shfl(degf, fb * 4 + i, 64);
      int grow = rowb + fb * 4 + i;
      bool ok = grow < n_rows;
      float pr = 0.0f;
#pragma unroll
      for (int tt = 0; tt < 4; ++tt) {
        size_t addr = (size_t)grow * 64 + 16 * tt + mm;
        float hold = ok ? __half2float(hdst[addr]) : 0.0f;
        float hv = tanhf(hold + bvt[tt] * deg_i + d[tt][i]);
        if (RO) {
          pr += hv * wrot[tt];
        } else {
          if (ok) hdst[addr] = __float2half(hv);
        }
      }
      if (RO) {
        pr += __shfl_xor(pr, 1, 64);
        pr += __shfl_xor(pr, 2, 64);
        pr += __shfl_xor(pr, 4, 64);
        pr += __shfl_xor(pr, 8, 64);
        if (mm == 0 && ok) scores[grow] = pr + brov;
      }
    }
  }
}

// Capped persistent grids (R9: full grids replicate preambles, 2.3x regression).
static inline int rowgrid(int n) {
  int want = (n + WPB - 1) / WPB;
  return want < 2048 ? want : 2048;
}
static inline int rowgrid16(int n) {
  int want = (n + WPB * 16 - 1) / (WPB * 16);
  return want < 2048 ? want : 2048;
}

extern "C" void kernel_launch(void* const* d_in, const int* in_sizes, int n_in,
                              void* d_out, int out_size, void* d_ws, size_t ws_size,
                              hipStream_t stream) {
  const float* vf    = (const float*)d_in[0];
  const float* cf    = (const float*)d_in[1];
  const int*   ev    = (const int*)d_in[2];
  const int*   ec    = (const int*)d_in[3];
  const float* W_ve1 = (const float*)d_in[4];
  const float* b_ve1 = (const float*)d_in[5];
  const float* W_ve2 = (const float*)d_in[6];
  const float* b_ve2 = (const float*)d_in[7];
  const float* W_ce1 = (const float*)d_in[8];
  const float* b_ce1 = (const float*)d_in[9];
  const float* W_ce2 = (const float*)d_in[10];
  const float* b_ce2 = (const float*)d_in[11];
  const float* W_v2c = (const float*)d_in[12];
  const float* b_v2c = (const float*)d_in[13];
  const float* W_c2v = (const float*)d_in[14];
  const float* b_c2v = (const float*)d_in[15];
  const float* W_ro  = (const float*)d_in[16];
  const float* b_ro  = (const float*)d_in[17];

  const int n_vars  = in_sizes[0] / 7;
  const int n_cons  = in_sizes[1] / 5;
  const int n_edges = in_sizes[2];
  const int R       = in_sizes[12] / (64 * 64);

  // Workspace ~50.5 MB (budget ~55 MB — R13 overflow lesson).
  char* p = (char*)d_ws;
  __half* h_var = (__half*)p; p += (size_t)n_vars * 64 * 2;   // 25.6 MB
  __half* h_con = (__half*)p; p += (size_t)n_cons * 64 * 2;   // 12.8 MB
  int*   rp_v   = (int*)p;   p += (size_t)(n_vars + 1) * 4;
  int*   rp_c   = (int*)p;   p += (size_t)(n_cons + 1) * 4;
  int*   deg_v  = (int*)p;   p += (size_t)n_vars * 4;
  int*   deg_c  = (int*)p;   p += (size_t)n_cons * 4;
  int*   esrc_v = (int*)p;   p += (size_t)n_edges * 4;
  int*   esrc_c = (int*)p;   p += (size_t)n_edges * 4;
  int*   bsums  = (int*)p;   p += 1024 * 4;
  h8*    wh_v2c = (h8*)p;    p += (size_t)R * 512 * 16;       // frag-major f16
  h8*    wh_c2v = (h8*)p;    p += (size_t)R * 512 * 16;
  // rank arrays ALIAS h_var (dead after placement; encoder writes h_var later).
  int*   rank_v = (int*)h_var;
  int*   rank_c = (int*)h_var + n_edges;

  const int nb_v = (n_vars + SCAN_EPB - 1) / SCAN_EPB;
  const int nb_c = (n_cons + SCAN_EPB - 1) / SCAN_EPB;

  hipMemsetAsync(deg_v, 0, (size_t)n_vars * 4, stream);
  hipMemsetAsync(deg_c, 0, (size_t)n_cons * 4, stream);
  hist_rank_kernel<<<(n_edges + 255) / 256, 256, 0, stream>>>(
      ev, ec, deg_v, deg_c, rank_v, rank_c, n_edges);

  // weight pre-conversion (once per launch; removes per-wave cvt preamble)
  wcvt_kernel<<<(R * 512 + 255) / 256, 256, 0, stream>>>(W_v2c, wh_v2c, R * 512);
  wcvt_kernel<<<(R * 512 + 255) / 256, 256, 0, stream>>>(W_c2v, wh_c2v, R * 512);

  scan_blocks_kernel<<<nb_v, 256, 0, stream>>>(deg_v, rp_v, bsums, n_vars);
  scan_sums_kernel<<<1, 256, 0, stream>>>(bsums, nb_v);
  scan_add_kernel<<<nb_v, 256, 0, stream>>>(rp_v, bsums, n_vars, n_edges);
  scan_blocks_kernel<<<nb_c, 256, 0, stream>>>(deg_c, rp_c, bsums, n_cons);
  scan_sums_kernel<<<1, 256, 0, stream>>>(bsums, nb_c);
  scan_add_kernel<<<nb_c, 256, 0, stream>>>(rp_c, bsums, n_cons, n_edges);

  {
    const int vrng = (n_vars + PLACE_NB - 1) / PLACE_NB;
    const int crng = (n_cons + PLACE_NB - 1) / PLACE_NB;
    for (int bpass = 0; bpass < PLACE_NB; ++bpass) {
      int vlo = bpass * vrng, vhi = vlo + vrng;
      int clo = bpass * crng, chi = clo + crng;
      place_range_kernel<<<1024, 256, 0, stream>>>(
          ev, ec, rp_v, rp_c, rank_v, rank_c, esrc_v, esrc_c, n_edges,
          vlo, vhi, clo, chi);
    }
  }

  // encoders overwrite h_var (rank arrays dead by now)
  encoder_kernel<7><<<rowgrid(n_vars), 256, 0, stream>>>(
      vf, W_ve1, b_ve1, W_ve2, b_ve2, h_var, n_vars);
  encoder_kernel<5><<<rowgrid(n_cons), 256, 0, stream>>>(
      cf, W_ce1, b_ce1, W_ce2, b_ce2, h_con, n_cons);

  for (int r = 0; r < R; ++r) {
    fused_mfma_kernel<false><<<rowgrid16(n_cons), 256, 0, stream>>>(
        h_con, h_var, rp_c, esrc_c,
        wh_v2c + (size_t)r * 512, b_v2c + (size_t)r * 64,
        nullptr, nullptr, nullptr, n_cons);
    if (r == R - 1) {
      fused_mfma_kernel<true><<<rowgrid16(n_vars), 256, 0, stream>>>(
          h_var, h_con, rp_v, esrc_v,
          wh_c2v + (size_t)r * 512, b_c2v + (size_t)r * 64,
          W_ro, b_ro, (float*)d_out, n_vars);
    } else {
      fused_mfma_kernel<false><<<rowgrid16(n_vars), 256, 0, stream>>>(
          h_var, h_con, rp_v, esrc_v,
          wh_c2v + (size_t)r * 512, b_c2v + (size_t)r * 64,
          nullptr, nullptr, nullptr, n_vars);
    }
  }
}

// Round 18
// 536.419 us; speedup vs baseline: 2.1897x; 1.0310x over previous
//
#include <hip/hip_runtime.h>
#include <hip/hip_bf16.h>
#include <hip/hip_fp16.h>

#define WPB 4          // waves per block (256 threads)
#define SCAN_EPB 1024  // elements per scan block (256 thr x 4)
#define PLACE_NB 4     // sequential destination-range passes for CSR placement

typedef _Float16 h8 __attribute__((ext_vector_type(8)));
typedef float f32x4 __attribute__((ext_vector_type(4)));

__device__ __forceinline__ float bcast(float v, int i) {
  return __builtin_bit_cast(float, __builtin_amdgcn_readlane(__builtin_bit_cast(int, v), i));
}
__device__ __forceinline__ h8 h8zero() {
  h8 r;
#pragma unroll
  for (int j = 0; j < 8; ++j) r[j] = (_Float16)0;
  return r;
}
__device__ __forceinline__ h8 cvt8(float4 a, float4 b) {
  h8 r;
  r[0] = (_Float16)a.x; r[1] = (_Float16)a.y; r[2] = (_Float16)a.z; r[3] = (_Float16)a.w;
  r[4] = (_Float16)b.x; r[5] = (_Float16)b.y; r[6] = (_Float16)b.z; r[7] = (_Float16)b.w;
  return r;
}

// ---------------- encoder body (shared) ----------------
// out = tanh(x @ W1^T + b1) @ W2^T + b2. One row per wave; W in VGPRs; f16 out.
template<int IN_F>
__device__ __forceinline__ void encoder_body(
    const float* __restrict__ x,
    const float* __restrict__ W1, const float* __restrict__ b1,
    const float* __restrict__ W2, const float* __restrict__ b2,
    __half* __restrict__ out, int n_rows, int bid, int nblocks) {
  int t = threadIdx.x;
  int wave = t >> 6, lane = t & 63;

  float w1reg[IN_F];
#pragma unroll
  for (int j = 0; j < IN_F; ++j) w1reg[j] = W1[lane * IN_F + j];
  float w2reg[64];
  const float4* W24 = (const float4*)(W2 + (size_t)lane * 64);
#pragma unroll
  for (int i = 0; i < 16; ++i) {
    float4 w = W24[i];
    w2reg[4 * i] = w.x; w2reg[4 * i + 1] = w.y;
    w2reg[4 * i + 2] = w.z; w2reg[4 * i + 3] = w.w;
  }
  float b1v = b1[lane], b2v = b2[lane];

  int stride = nblocks * WPB;
  for (int row = bid * WPB + wave; row < n_rows; row += stride) {
    float xl = 0.0f;
    if (lane < IN_F) xl = x[(size_t)row * IN_F + lane];
    float h = b1v;
#pragma unroll
    for (int j = 0; j < IN_F; ++j) h += w1reg[j] * bcast(xl, j);
    float hid = tanhf(h);

    float o0 = b2v, o1 = 0.f, o2 = 0.f, o3 = 0.f;
#pragma unroll
    for (int i = 0; i < 64; i += 4) {
      o0 += w2reg[i]     * bcast(hid, i);
      o1 += w2reg[i + 1] * bcast(hid, i + 1);
      o2 += w2reg[i + 2] * bcast(hid, i + 2);
      o3 += w2reg[i + 3] * bcast(hid, i + 3);
    }
    out[(size_t)row * 64 + lane] = __float2half((o0 + o1) + (o2 + o3));
  }
}

template<int IN_F>
__global__ __launch_bounds__(256, 4) void encoder_kernel(
    const float* __restrict__ x,
    const float* __restrict__ W1, const float* __restrict__ b1,
    const float* __restrict__ W2, const float* __restrict__ b2,
    __half* __restrict__ out, int n_rows) {
  encoder_body<IN_F>(x, W1, b1, W2, b2, out, n_rows, blockIdx.x, gridDim.x);
}

// ---------------- heterogeneous: encoder<7> + hist_rank ----------------
// hist_rank is TCC-atomic-transaction-bound (VALUBusy 0.4%) — encoder<7> is
// independent of the CSR and runs in its latency shadow. Blocks [0,encB) do
// the encoder; the rest histogram edges into merged deg[] and emit per-edge
// ranks (making placement atomic-free).
__global__ __launch_bounds__(256) void enc7_hist_kernel(
    const float* __restrict__ x,
    const float* __restrict__ W1, const float* __restrict__ b1,
    const float* __restrict__ W2, const float* __restrict__ b2,
    __half* __restrict__ hvar, int n_rows,
    const int* __restrict__ ev, const int* __restrict__ ec,
    int* __restrict__ deg, int* __restrict__ rank_v, int* __restrict__ rank_c,
    int n_edges, int n_vars, int encB) {
  int bid = blockIdx.x;
  if (bid >= encB) {
    int e = (bid - encB) * 256 + threadIdx.x;
    if (e < n_edges) {
      rank_v[e] = atomicAdd(&deg[ev[e]], 1);
      rank_c[e] = atomicAdd(&deg[n_vars + ec[e]], 1);
    }
    return;
  }
  encoder_body<7>(x, W1, b1, W2, b2, hvar, n_rows, bid, encB);
}

// ---------------- weight pre-conversion ----------------
// Fragment-major f16 for the fused kernels' B-operands (8 coalesced dwordx4
// per wave preamble, zero cvts). total = R*512.
__global__ __launch_bounds__(256) void wcvt_kernel(
    const float* __restrict__ W, h8* __restrict__ Wh, int total) {
  int tid = blockIdx.x * 256 + threadIdx.x;
  if (tid >= total) return;
  int l = tid & 63;
  int f = (tid >> 6) & 7;
  int r = tid >> 9;
  int tt = f >> 1, s = f & 1;
  const float* wp = W + (size_t)r * 4096 + (size_t)(16 * tt + (l & 15)) * 64
                    + 32 * s + 8 * (l >> 4);
  Wh[tid] = cvt8(*(const float4*)wp, *(const float4*)(wp + 4));
}

// ---------------- scan (single merged chain over [vars | cons]) ----------------
__global__ __launch_bounds__(256) void scan_blocks_kernel(
    const int* __restrict__ in, int* __restrict__ out,
    int* __restrict__ bsums, int n) {
  __shared__ int s[256];
  int t = threadIdx.x;
  int base = blockIdx.x * SCAN_EPB + t * 4;
  int v[4]; int local = 0;
#pragma unroll
  for (int j = 0; j < 4; ++j) {
    int idx = base + j;
    v[j] = (idx < n) ? in[idx] : 0;
    local += v[j];
  }
  s[t] = local;
  __syncthreads();
  for (int off = 1; off < 256; off <<= 1) {
    int val = (t >= off) ? s[t - off] : 0;
    __syncthreads();
    s[t] += val;
    __syncthreads();
  }
  int run = s[t] - local;
#pragma unroll
  for (int j = 0; j < 4; ++j) {
    int idx = base + j;
    if (idx < n) out[idx] = run;
    run += v[j];
  }
  if (t == 255) bsums[blockIdx.x] = s[255];
}

__global__ __launch_bounds__(256) void scan_sums_kernel(int* __restrict__ bsums, int nb) {
  __shared__ int s[256];
  int t = threadIdx.x;
  int base = t * 4;
  int v[4]; int local = 0;
#pragma unroll
  for (int j = 0; j < 4; ++j) {
    int idx = base + j;
    v[j] = (idx < nb) ? bsums[idx] : 0;
    local += v[j];
  }
  s[t] = local;
  __syncthreads();
  for (int off = 1; off < 256; off <<= 1) {
    int val = (t >= off) ? s[t - off] : 0;
    __syncthreads();
    s[t] += val;
    __syncthreads();
  }
  int run = s[t] - local;
#pragma unroll
  for (int j = 0; j < 4; ++j) {
    int idx = base + j;
    if (idx < nb) bsums[idx] = run;
    run += v[j];
  }
}

__global__ __launch_bounds__(256) void scan_add_kernel(
    int* __restrict__ out, const int* __restrict__ bsums, int n, int total) {
  int t = threadIdx.x;
  int base = blockIdx.x * SCAN_EPB + t * 4;
  int add = bsums[blockIdx.x];
#pragma unroll
  for (int j = 0; j < 4; ++j) {
    int idx = base + j;
    if (idx < n) out[idx] += add;
  }
  if (blockIdx.x == 0 && t == 0) out[n] = total;
}

// Atomic-free range-partitioned placement into the merged esrc array:
// v-dst slots land in [0,E), c-dst slots in [E,2E). Range passes keep the
// scattered-write working set L2-local (R7 lesson).
__global__ __launch_bounds__(256) void place_range_kernel(
    const int* __restrict__ ev, const int* __restrict__ ec,
    const int* __restrict__ rp,
    const int* __restrict__ rank_v, const int* __restrict__ rank_c,
    int* __restrict__ esrc, int n_edges, int n_vars,
    int vlo, int vhi, int clo, int chi) {
  int stride = gridDim.x * 256;
  for (int e = blockIdx.x * 256 + threadIdx.x; e < n_edges; e += stride) {
    int v = ev[e], c = ec[e];
    if (c >= clo && c < chi) esrc[rp[n_vars + c] + rank_c[e]] = v;
    if (v >= vlo && v < vhi) esrc[rp[v] + rank_v[e]] = c;
  }
}

// ---------------- MFMA fused aggregate + linear + tanh (+ optional readout) ----------------
// 16 consecutive dest rows per wave. Gather in MFMA A-operand layout, 4 edges
// per iteration (12 loads in flight). B-fragments loaded pre-converted.
// C/D: col=lane&15, row=(lane>>4)*4+reg (m89).
template<bool RO>
__global__ __launch_bounds__(256, 4) void fused_mfma_kernel(
    __half* __restrict__ hdst, const __half* __restrict__ hsrc,
    const int* __restrict__ rp, const int* __restrict__ esrc,
    const h8* __restrict__ Wh, const float* __restrict__ b,
    const float* __restrict__ Wro, const float* __restrict__ bro,
    float* __restrict__ scores, int n_rows) {
  int t = threadIdx.x;
  int wave = t >> 6, lane = t & 63;
  int mm = lane & 15;   // dest-row slot within the 16-row batch
  int fb = lane >> 4;   // feature-block 0..3

  h8 Bf[4][2];
  float bvt[4], wrot[4];
#pragma unroll
  for (int tt = 0; tt < 4; ++tt) {
#pragma unroll
    for (int s = 0; s < 2; ++s) Bf[tt][s] = Wh[(tt * 2 + s) * 64 + lane];
    bvt[tt] = b[16 * tt + mm];
    wrot[tt] = RO ? Wro[16 * tt + mm] : 0.0f;
  }
  float brov = RO ? bro[0] : 0.0f;

  const float4* rows4 = (const float4*)hsrc;  // 8 float4 per 64-half row
  const h8 zh = h8zero();

  int stride16 = gridDim.x * WPB * 16;
  for (int rowb = (blockIdx.x * WPB + wave) * 16; rowb < n_rows; rowb += stride16) {
    int mrow = rowb + mm;
    int mc = (mrow < n_rows) ? mrow : n_rows - 1;
    int p = rp[mc], end = rp[mc + 1];
    float degf = (float)(end - p);

    h8 a0 = zh, a1 = zh;
    while (__any(p < end)) {
      bool v0 = p < end, v1 = p + 1 < end, v2 = p + 2 < end, v3 = p + 3 < end;
      int i0 = v0 ? p : 0;
      int i1 = v1 ? p + 1 : 0;
      int i2 = v2 ? p + 2 : 0;
      int i3 = v3 ? p + 3 : 0;
      int s0 = esrc[i0];
      int s1 = esrc[i1];
      int s2 = esrc[i2];
      int s3 = esrc[i3];
      float4 q0a = rows4[(size_t)s0 * 8 + fb];
      float4 q0b = rows4[(size_t)s0 * 8 + 4 + fb];
      float4 q1a = rows4[(size_t)s1 * 8 + fb];
      float4 q1b = rows4[(size_t)s1 * 8 + 4 + fb];
      float4 q2a = rows4[(size_t)s2 * 8 + fb];
      float4 q2b = rows4[(size_t)s2 * 8 + 4 + fb];
      float4 q3a = rows4[(size_t)s3 * 8 + fb];
      float4 q3b = rows4[(size_t)s3 * 8 + 4 + fb];
      a0 += v0 ? __builtin_bit_cast(h8, q0a) : zh;
      a1 += v0 ? __builtin_bit_cast(h8, q0b) : zh;
      a0 += v1 ? __builtin_bit_cast(h8, q1a) : zh;
      a1 += v1 ? __builtin_bit_cast(h8, q1b) : zh;
      a0 += v2 ? __builtin_bit_cast(h8, q2a) : zh;
      a1 += v2 ? __builtin_bit_cast(h8, q2b) : zh;
      a0 += v3 ? __builtin_bit_cast(h8, q3a) : zh;
      a1 += v3 ? __builtin_bit_cast(h8, q3b) : zh;
      p += 4;
    }

    // D[16x64] = A @ W^T : 4 n-tiles x 2 K-steps
    f32x4 d[4];
#pragma unroll
    for (int tt = 0; tt < 4; ++tt) {
      f32x4 dz; dz[0] = 0.f; dz[1] = 0.f; dz[2] = 0.f; dz[3] = 0.f;
      d[tt] = __builtin_amdgcn_mfma_f32_16x16x32_f16(a0, Bf[tt][0], dz, 0, 0, 0);
      d[tt] = __builtin_amdgcn_mfma_f32_16x16x32_f16(a1, Bf[tt][1], d[tt], 0, 0, 0);
    }

    // epilogue: lane l, reg i, tile t -> row rowb + 4*fb + i, col 16t + mm
#pragma unroll
    for (int i = 0; i < 4; ++i) {
      float deg_i = __shfl(degf, fb * 4 + i, 64);
      int grow = rowb + fb * 4 + i;
      bool ok = grow < n_rows;
      float pr = 0.0f;
#pragma unroll
      for (int tt = 0; tt < 4; ++tt) {
        size_t addr = (size_t)grow * 64 + 16 * tt + mm;
        float hold = ok ? __half2float(hdst[addr]) : 0.0f;
        float hv = tanhf(hold + bvt[tt] * deg_i + d[tt][i]);
        if (RO) {
          pr += hv * wrot[tt];
        } else {
          if (ok) hdst[addr] = __float2half(hv);
        }
      }
      if (RO) {
        pr += __shfl_xor(pr, 1, 64);
        pr += __shfl_xor(pr, 2, 64);
        pr += __shfl_xor(pr, 4, 64);
        pr += __shfl_xor(pr, 8, 64);
        if (mm == 0 && ok) scores[grow] = pr + brov;
      }
    }
  }
}

// Capped persistent grids (R9: full grids replicate preambles, 2.3x regression).
static inline int rowgrid(int n) {
  int want = (n + WPB - 1) / WPB;
  return want < 2048 ? want : 2048;
}
static inline int rowgrid16(int n) {
  int want = (n + WPB * 16 - 1) / (WPB * 16);
  return want < 2048 ? want : 2048;
}

extern "C" void kernel_launch(void* const* d_in, const int* in_sizes, int n_in,
                              void* d_out, int out_size, void* d_ws, size_t ws_size,
                              hipStream_t stream) {
  const float* vf    = (const float*)d_in[0];
  const float* cf    = (const float*)d_in[1];
  const int*   ev    = (const int*)d_in[2];
  const int*   ec    = (const int*)d_in[3];
  const float* W_ve1 = (const float*)d_in[4];
  const float* b_ve1 = (const float*)d_in[5];
  const float* W_ve2 = (const float*)d_in[6];
  const float* b_ve2 = (const float*)d_in[7];
  const float* W_ce1 = (const float*)d_in[8];
  const float* b_ce1 = (const float*)d_in[9];
  const float* W_ce2 = (const float*)d_in[10];
  const float* b_ce2 = (const float*)d_in[11];
  const float* W_v2c = (const float*)d_in[12];
  const float* b_v2c = (const float*)d_in[13];
  const float* W_c2v = (const float*)d_in[14];
  const float* b_c2v = (const float*)d_in[15];
  const float* W_ro  = (const float*)d_in[16];
  const float* b_ro  = (const float*)d_in[17];

  const int n_vars  = in_sizes[0] / 7;
  const int n_cons  = in_sizes[1] / 5;
  const int n_edges = in_sizes[2];
  const int R       = in_sizes[12] / (64 * 64);
  const int n_nodes = n_vars + n_cons;

  // Workspace ~50.5 MB (budget ~55 MB — R13 overflow lesson).
  char* p = (char*)d_ws;
  __half* h_var = (__half*)p; p += (size_t)n_vars * 64 * 2;   // 25.6 MB
  __half* h_con = (__half*)p; p += (size_t)n_cons * 64 * 2;   // 12.8 MB
  int*   rp     = (int*)p;   p += (size_t)(n_nodes + 1) * 4;  // merged [vars|cons]
  int*   deg    = (int*)p;   p += (size_t)n_nodes * 4;        // merged
  int*   esrc   = (int*)p;   p += (size_t)2 * n_edges * 4;    // v-slots [0,E), c-slots [E,2E)
  int*   bsums  = (int*)p;   p += 1024 * 4;
  h8*    wh_v2c = (h8*)p;    p += (size_t)R * 512 * 16;       // frag-major f16
  h8*    wh_c2v = (h8*)p;    p += (size_t)R * 512 * 16;
  // rank arrays ALIAS h_con (dead after placement; encoder<5> writes h_con
  // only after all place passes). 9.6 MB <= 12.8 MB. h_var hosts encoder<7>
  // output concurrently with hist (disjoint regions).
  int*   rank_v = (int*)h_con;
  int*   rank_c = (int*)h_con + n_edges;

  const int nb = (n_nodes + SCAN_EPB - 1) / SCAN_EPB;
  const int encB = rowgrid(n_vars);
  const int histB = (n_edges + 255) / 256;

  hipMemsetAsync(deg, 0, (size_t)n_nodes * 4, stream);

  // heterogeneous: encoder<7> (VALU) in hist_rank's atomic-latency shadow
  enc7_hist_kernel<<<encB + histB, 256, 0, stream>>>(
      vf, W_ve1, b_ve1, W_ve2, b_ve2, h_var, n_vars,
      ev, ec, deg, rank_v, rank_c, n_edges, n_vars, encB);

  // weight pre-conversion (once per launch)
  wcvt_kernel<<<(R * 512 + 255) / 256, 256, 0, stream>>>(W_v2c, wh_v2c, R * 512);
  wcvt_kernel<<<(R * 512 + 255) / 256, 256, 0, stream>>>(W_c2v, wh_c2v, R * 512);

  // single merged scan chain -> rp (tail = 2E)
  scan_blocks_kernel<<<nb, 256, 0, stream>>>(deg, rp, bsums, n_nodes);
  scan_sums_kernel<<<1, 256, 0, stream>>>(bsums, nb);
  scan_add_kernel<<<nb, 256, 0, stream>>>(rp, bsums, n_nodes, 2 * n_edges);

  {
    const int vrng = (n_vars + PLACE_NB - 1) / PLACE_NB;
    const int crng = (n_cons + PLACE_NB - 1) / PLACE_NB;
    for (int bpass = 0; bpass < PLACE_NB; ++bpass) {
      int vlo = bpass * vrng, vhi = vlo + vrng;
      int clo = bpass * crng, chi = clo + crng;
      place_range_kernel<<<1024, 256, 0, stream>>>(
          ev, ec, rp, rank_v, rank_c, esrc, n_edges, n_vars,
          vlo, vhi, clo, chi);
    }
  }

  // encoder<5> AFTER placement (its output region hosted the rank arrays)
  encoder_kernel<5><<<rowgrid(n_cons), 256, 0, stream>>>(
      cf, W_ce1, b_ce1, W_ce2, b_ce2, h_con, n_cons);

  for (int r = 0; r < R; ++r) {
    fused_mfma_kernel<false><<<rowgrid16(n_cons), 256, 0, stream>>>(
        h_con, h_var, rp + n_vars, esrc,
        wh_v2c + (size_t)r * 512, b_v2c + (size_t)r * 64,
        nullptr, nullptr, nullptr, n_cons);
    if (r == R - 1) {
      fused_mfma_kernel<true><<<rowgrid16(n_vars), 256, 0, stream>>>(
          h_var, h_con, rp, esrc,
          wh_c2v + (size_t)r * 512, b_c2v + (size_t)r * 64,
          W_ro, b_ro, (float*)d_out, n_vars);
    } else {
      fused_mfma_kernel<false><<<rowgrid16(n_vars), 256, 0, stream>>>(
          h_var, h_con, rp, esrc,
          wh_c2v + (size_t)r * 512, b_c2v + (size_t)r * 64,
          nullptr, nullptr, nullptr, n_vars);
    }
  }
}

// Round 19
// 534.915 us; speedup vs baseline: 2.1959x; 1.0028x over previous
//
#include <hip/hip_runtime.h>
#include <hip/hip_bf16.h>
#include <hip/hip_fp16.h>

#define WPB 4          // waves per block (256 threads)
#define SCAN_EPB 1024  // elements per scan block (256 thr x 4)
#define PLACE_NB 2     // sequential destination-range passes for CSR placement

typedef _Float16 h8 __attribute__((ext_vector_type(8)));
typedef float f32x4 __attribute__((ext_vector_type(4)));

__device__ __forceinline__ float bcast(float v, int i) {
  return __builtin_bit_cast(float, __builtin_amdgcn_readlane(__builtin_bit_cast(int, v), i));
}
__device__ __forceinline__ h8 h8zero() {
  h8 r;
#pragma unroll
  for (int j = 0; j < 8; ++j) r[j] = (_Float16)0;
  return r;
}
__device__ __forceinline__ h8 cvt8(float4 a, float4 b) {
  h8 r;
  r[0] = (_Float16)a.x; r[1] = (_Float16)a.y; r[2] = (_Float16)a.z; r[3] = (_Float16)a.w;
  r[4] = (_Float16)b.x; r[5] = (_Float16)b.y; r[6] = (_Float16)b.z; r[7] = (_Float16)b.w;
  return r;
}

// ---------------- encoders ----------------
// out = tanh(x @ W1^T + b1) @ W2^T + b2. One row per wave; W in VGPRs; f16 out.
// Persistent capped grid (R9: full grids replicate the W->VGPR preamble).
// Kept as a DEDICATED kernel: fusing with the 4-VGPR hist kernel drags hist's
// occupancy 70%->42% and stretches it 96->177 us (R18 lesson).
template<int IN_F>
__global__ __launch_bounds__(256, 4) void encoder_kernel(
    const float* __restrict__ x,
    const float* __restrict__ W1, const float* __restrict__ b1,
    const float* __restrict__ W2, const float* __restrict__ b2,
    __half* __restrict__ out, int n_rows) {
  int t = threadIdx.x;
  int wave = t >> 6, lane = t & 63;

  float w1reg[IN_F];
#pragma unroll
  for (int j = 0; j < IN_F; ++j) w1reg[j] = W1[lane * IN_F + j];
  float w2reg[64];
  const float4* W24 = (const float4*)(W2 + (size_t)lane * 64);
#pragma unroll
  for (int i = 0; i < 16; ++i) {
    float4 w = W24[i];
    w2reg[4 * i] = w.x; w2reg[4 * i + 1] = w.y;
    w2reg[4 * i + 2] = w.z; w2reg[4 * i + 3] = w.w;
  }
  float b1v = b1[lane], b2v = b2[lane];

  int stride = gridDim.x * WPB;
  for (int row = blockIdx.x * WPB + wave; row < n_rows; row += stride) {
    float xl = 0.0f;
    if (lane < IN_F) xl = x[(size_t)row * IN_F + lane];
    float h = b1v;
#pragma unroll
    for (int j = 0; j < IN_F; ++j) h += w1reg[j] * bcast(xl, j);
    float hid = tanhf(h);

    float o0 = b2v, o1 = 0.f, o2 = 0.f, o3 = 0.f;
#pragma unroll
    for (int i = 0; i < 64; i += 4) {
      o0 += w2reg[i]     * bcast(hid, i);
      o1 += w2reg[i + 1] * bcast(hid, i + 1);
      o2 += w2reg[i + 2] * bcast(hid, i + 2);
      o3 += w2reg[i + 3] * bcast(hid, i + 3);
    }
    out[(size_t)row * 64 + lane] = __float2half((o0 + o1) + (o2 + o3));
  }
}

// ---------------- CSR build ----------------
// Single scattered-atomic pass (~26 G atomics/s transaction floor — R12/R18
// confirmed immovable) also emits per-edge ranks -> placement atomic-free.
// 4 VGPR -> 70% occupancy; keep this kernel lean (R18 lesson).
__global__ __launch_bounds__(256) void hist_rank_kernel(
    const int* __restrict__ ev, const int* __restrict__ ec,
    int* __restrict__ deg, int* __restrict__ rank_v, int* __restrict__ rank_c,
    int n_edges, int n_vars) {
  int e = blockIdx.x * 256 + threadIdx.x;
  if (e >= n_edges) return;
  rank_v[e] = atomicAdd(&deg[ev[e]], 1);
  rank_c[e] = atomicAdd(&deg[n_vars + ec[e]], 1);
}

// ---------------- weight pre-conversion ----------------
// Fragment-major f16 for the fused kernels' B-operands. total = R*512.
__global__ __launch_bounds__(256) void wcvt_kernel(
    const float* __restrict__ W, h8* __restrict__ Wh, int total) {
  int tid = blockIdx.x * 256 + threadIdx.x;
  if (tid >= total) return;
  int l = tid & 63;
  int f = (tid >> 6) & 7;
  int r = tid >> 9;
  int tt = f >> 1, s = f & 1;
  const float* wp = W + (size_t)r * 4096 + (size_t)(16 * tt + (l & 15)) * 64
                    + 32 * s + 8 * (l >> 4);
  Wh[tid] = cvt8(*(const float4*)wp, *(const float4*)(wp + 4));
}

// ---------------- scan (single merged chain over [vars | cons]) ----------------
__global__ __launch_bounds__(256) void scan_blocks_kernel(
    const int* __restrict__ in, int* __restrict__ out,
    int* __restrict__ bsums, int n) {
  __shared__ int s[256];
  int t = threadIdx.x;
  int base = blockIdx.x * SCAN_EPB + t * 4;
  int v[4]; int local = 0;
#pragma unroll
  for (int j = 0; j < 4; ++j) {
    int idx = base + j;
    v[j] = (idx < n) ? in[idx] : 0;
    local += v[j];
  }
  s[t] = local;
  __syncthreads();
  for (int off = 1; off < 256; off <<= 1) {
    int val = (t >= off) ? s[t - off] : 0;
    __syncthreads();
    s[t] += val;
    __syncthreads();
  }
  int run = s[t] - local;
#pragma unroll
  for (int j = 0; j < 4; ++j) {
    int idx = base + j;
    if (idx < n) out[idx] = run;
    run += v[j];
  }
  if (t == 255) bsums[blockIdx.x] = s[255];
}

__global__ __launch_bounds__(256) void scan_sums_kernel(int* __restrict__ bsums, int nb) {
  __shared__ int s[256];
  int t = threadIdx.x;
  int base = t * 4;
  int v[4]; int local = 0;
#pragma unroll
  for (int j = 0; j < 4; ++j) {
    int idx = base + j;
    v[j] = (idx < nb) ? bsums[idx] : 0;
    local += v[j];
  }
  s[t] = local;
  __syncthreads();
  for (int off = 1; off < 256; off <<= 1) {
    int val = (t >= off) ? s[t - off] : 0;
    __syncthreads();
    s[t] += val;
    __syncthreads();
  }
  int run = s[t] - local;
#pragma unroll
  for (int j = 0; j < 4; ++j) {
    int idx = base + j;
    if (idx < nb) bsums[idx] = run;
    run += v[j];
  }
}

__global__ __launch_bounds__(256) void scan_add_kernel(
    int* __restrict__ out, const int* __restrict__ bsums, int n, int total) {
  int t = threadIdx.x;
  int base = blockIdx.x * SCAN_EPB + t * 4;
  int add = bsums[blockIdx.x];
#pragma unroll
  for (int j = 0; j < 4; ++j) {
    int idx = base + j;
    if (idx < n) out[idx] += add;
  }
  if (blockIdx.x == 0 && t == 0) out[n] = total;
}

// Atomic-free range-partitioned placement into the merged esrc array:
// v-dst slots land in [0,E), c-dst slots in [E,2E). Range passes keep the
// scattered-write working set L2-local (R7 lesson; 2 passes = 2.4 MB/side).
__global__ __launch_bounds__(256) void place_range_kernel(
    const int* __restrict__ ev, const int* __restrict__ ec,
    const int* __restrict__ rp,
    const int* __restrict__ rank_v, const int* __restrict__ rank_c,
    int* __restrict__ esrc, int n_edges, int n_vars,
    int vlo, int vhi, int clo, int chi) {
  int stride = gridDim.x * 256;
  for (int e = blockIdx.x * 256 + threadIdx.x; e < n_edges; e += stride) {
    int v = ev[e], c = ec[e];
    if (c >= clo && c < chi) esrc[rp[n_vars + c] + rank_c[e]] = v;
    if (v >= vlo && v < vhi) esrc[rp[v] + rank_v[e]] = c;
  }
}

// ---------------- MFMA fused aggregate + linear + tanh (+ optional readout) ----------------
// 16 consecutive dest rows per wave. Gather in MFMA A-operand layout, 4 edges
// per iteration (12 loads in flight). B-fragments loaded pre-converted.
// C/D: col=lane&15, row=(lane>>4)*4+reg (m89).
template<bool RO>
__global__ __launch_bounds__(256, 4) void fused_mfma_kernel(
    __half* __restrict__ hdst, const __half* __restrict__ hsrc,
    const int* __restrict__ rp, const int* __restrict__ esrc,
    const h8* __restrict__ Wh, const float* __restrict__ b,
    const float* __restrict__ Wro, const float* __restrict__ bro,
    float* __restrict__ scores, int n_rows) {
  int t = threadIdx.x;
  int wave = t >> 6, lane = t & 63;
  int mm = lane & 15;   // dest-row slot within the 16-row batch
  int fb = lane >> 4;   // feature-block 0..3

  h8 Bf[4][2];
  float bvt[4], wrot[4];
#pragma unroll
  for (int tt = 0; tt < 4; ++tt) {
#pragma unroll
    for (int s = 0; s < 2; ++s) Bf[tt][s] = Wh[(tt * 2 + s) * 64 + lane];
    bvt[tt] = b[16 * tt + mm];
    wrot[tt] = RO ? Wro[16 * tt + mm] : 0.0f;
  }
  float brov = RO ? bro[0] : 0.0f;

  const float4* rows4 = (const float4*)hsrc;  // 8 float4 per 64-half row
  const h8 zh = h8zero();

  int stride16 = gridDim.x * WPB * 16;
  for (int rowb = (blockIdx.x * WPB + wave) * 16; rowb < n_rows; rowb += stride16) {
    int mrow = rowb + mm;
    int mc = (mrow < n_rows) ? mrow : n_rows - 1;
    int p = rp[mc], end = rp[mc + 1];
    float degf = (float)(end - p);

    h8 a0 = zh, a1 = zh;
    while (__any(p < end)) {
      bool v0 = p < end, v1 = p + 1 < end, v2 = p + 2 < end, v3 = p + 3 < end;
      int i0 = v0 ? p : 0;
      int i1 = v1 ? p + 1 : 0;
      int i2 = v2 ? p + 2 : 0;
      int i3 = v3 ? p + 3 : 0;
      int s0 = esrc[i0];
      int s1 = esrc[i1];
      int s2 = esrc[i2];
      int s3 = esrc[i3];
      float4 q0a = rows4[(size_t)s0 * 8 + fb];
      float4 q0b = rows4[(size_t)s0 * 8 + 4 + fb];
      float4 q1a = rows4[(size_t)s1 * 8 + fb];
      float4 q1b = rows4[(size_t)s1 * 8 + 4 + fb];
      float4 q2a = rows4[(size_t)s2 * 8 + fb];
      float4 q2b = rows4[(size_t)s2 * 8 + 4 + fb];
      float4 q3a = rows4[(size_t)s3 * 8 + fb];
      float4 q3b = rows4[(size_t)s3 * 8 + 4 + fb];
      a0 += v0 ? __builtin_bit_cast(h8, q0a) : zh;
      a1 += v0 ? __builtin_bit_cast(h8, q0b) : zh;
      a0 += v1 ? __builtin_bit_cast(h8, q1a) : zh;
      a1 += v1 ? __builtin_bit_cast(h8, q1b) : zh;
      a0 += v2 ? __builtin_bit_cast(h8, q2a) : zh;
      a1 += v2 ? __builtin_bit_cast(h8, q2b) : zh;
      a0 += v3 ? __builtin_bit_cast(h8, q3a) : zh;
      a1 += v3 ? __builtin_bit_cast(h8, q3b) : zh;
      p += 4;
    }

    // D[16x64] = A @ W^T : 4 n-tiles x 2 K-steps
    f32x4 d[4];
#pragma unroll
    for (int tt = 0; tt < 4; ++tt) {
      f32x4 dz; dz[0] = 0.f; dz[1] = 0.f; dz[2] = 0.f; dz[3] = 0.f;
      d[tt] = __builtin_amdgcn_mfma_f32_16x16x32_f16(a0, Bf[tt][0], dz, 0, 0, 0);
      d[tt] = __builtin_amdgcn_mfma_f32_16x16x32_f16(a1, Bf[tt][1], d[tt], 0, 0, 0);
    }

    // epilogue: lane l, reg i, tile t -> row rowb + 4*fb + i, col 16t + mm
#pragma unroll
    for (int i = 0; i < 4; ++i) {
      float deg_i = __shfl(degf, fb * 4 + i, 64);
      int grow = rowb + fb * 4 + i;
      bool ok = grow < n_rows;
      float pr = 0.0f;
#pragma unroll
      for (int tt = 0; tt < 4; ++tt) {
        size_t addr = (size_t)grow * 64 + 16 * tt + mm;
        float hold = ok ? __half2float(hdst[addr]) : 0.0f;
        float hv = tanhf(hold + bvt[tt] * deg_i + d[tt][i]);
        if (RO) {
          pr += hv * wrot[tt];
        } else {
          if (ok) hdst[addr] = __float2half(hv);
        }
      }
      if (RO) {
        pr += __shfl_xor(pr, 1, 64);
        pr += __shfl_xor(pr, 2, 64);
        pr += __shfl_xor(pr, 4, 64);
        pr += __shfl_xor(pr, 8, 64);
        if (mm == 0 && ok) scores[grow] = pr + brov;
      }
    }
  }
}

// Capped persistent grids (R9: full grids replicate preambles, 2.3x regression).
static inline int rowgrid(int n) {
  int want = (n + WPB - 1) / WPB;
  return want < 2048 ? want : 2048;
}
static inline int rowgrid16(int n) {
  int want = (n + WPB * 16 - 1) / (WPB * 16);
  return want < 2048 ? want : 2048;
}

extern "C" void kernel_launch(void* const* d_in, const int* in_sizes, int n_in,
                              void* d_out, int out_size, void* d_ws, size_t ws_size,
                              hipStream_t stream) {
  const float* vf    = (const float*)d_in[0];
  const float* cf    = (const float*)d_in[1];
  const int*   ev    = (const int*)d_in[2];
  const int*   ec    = (const int*)d_in[3];
  const float* W_ve1 = (const float*)d_in[4];
  const float* b_ve1 = (const float*)d_in[5];
  const float* W_ve2 = (const float*)d_in[6];
  const float* b_ve2 = (const float*)d_in[7];
  const float* W_ce1 = (const float*)d_in[8];
  const float* b_ce1 = (const float*)d_in[9];
  const float* W_ce2 = (const float*)d_in[10];
  const float* b_ce2 = (const float*)d_in[11];
  const float* W_v2c = (const float*)d_in[12];
  const float* b_v2c = (const float*)d_in[13];
  const float* W_c2v = (const float*)d_in[14];
  const float* b_c2v = (const float*)d_in[15];
  const float* W_ro  = (const float*)d_in[16];
  const float* b_ro  = (const float*)d_in[17];

  const int n_vars  = in_sizes[0] / 7;
  const int n_cons  = in_sizes[1] / 5;
  const int n_edges = in_sizes[2];
  const int R       = in_sizes[12] / (64 * 64);
  const int n_nodes = n_vars + n_cons;

  // Workspace ~50.5 MB (budget ~55 MB — R13 overflow lesson).
  char* p = (char*)d_ws;
  __half* h_var = (__half*)p; p += (size_t)n_vars * 64 * 2;   // 25.6 MB
  __half* h_con = (__half*)p; p += (size_t)n_cons * 64 * 2;   // 12.8 MB
  int*   rp     = (int*)p;   p += (size_t)(n_nodes + 1) * 4;  // merged [vars|cons]
  int*   deg    = (int*)p;   p += (size_t)n_nodes * 4;        // merged
  int*   esrc   = (int*)p;   p += (size_t)2 * n_edges * 4;    // v-slots [0,E), c-slots [E,2E)
  int*   bsums  = (int*)p;   p += 1024 * 4;
  h8*    wh_v2c = (h8*)p;    p += (size_t)R * 512 * 16;       // frag-major f16
  h8*    wh_c2v = (h8*)p;    p += (size_t)R * 512 * 16;
  // rank arrays ALIAS h_con (dead after placement; encoder<5> writes h_con
  // only after all place passes). 9.6 MB <= 12.8 MB.
  int*   rank_v = (int*)h_con;
  int*   rank_c = (int*)h_con + n_edges;

  const int nb = (n_nodes + SCAN_EPB - 1) / SCAN_EPB;

  hipMemsetAsync(deg, 0, (size_t)n_nodes * 4, stream);
  hist_rank_kernel<<<(n_edges + 255) / 256, 256, 0, stream>>>(
      ev, ec, deg, rank_v, rank_c, n_edges, n_vars);

  // encoder<7> (h_var region is disjoint from rank arrays)
  encoder_kernel<7><<<rowgrid(n_vars), 256, 0, stream>>>(
      vf, W_ve1, b_ve1, W_ve2, b_ve2, h_var, n_vars);

  // weight pre-conversion (once per launch)
  wcvt_kernel<<<(R * 512 + 255) / 256, 256, 0, stream>>>(W_v2c, wh_v2c, R * 512);
  wcvt_kernel<<<(R * 512 + 255) / 256, 256, 0, stream>>>(W_c2v, wh_c2v, R * 512);

  // single merged scan chain -> rp (tail = 2E)
  scan_blocks_kernel<<<nb, 256, 0, stream>>>(deg, rp, bsums, n_nodes);
  scan_sums_kernel<<<1, 256, 0, stream>>>(bsums, nb);
  scan_add_kernel<<<nb, 256, 0, stream>>>(rp, bsums, n_nodes, 2 * n_edges);

  {
    const int vrng = (n_vars + PLACE_NB - 1) / PLACE_NB;
    const int crng = (n_cons + PLACE_NB - 1) / PLACE_NB;
    for (int bpass = 0; bpass < PLACE_NB; ++bpass) {
      int vlo = bpass * vrng, vhi = vlo + vrng;
      int clo = bpass * crng, chi = clo + crng;
      place_range_kernel<<<1024, 256, 0, stream>>>(
          ev, ec, rp, rank_v, rank_c, esrc, n_edges, n_vars,
          vlo, vhi, clo, chi);
    }
  }

  // encoder<5> AFTER placement (its output region hosted the rank arrays)
  encoder_kernel<5><<<rowgrid(n_cons), 256, 0, stream>>>(
      cf, W_ce1, b_ce1, W_ce2, b_ce2, h_con, n_cons);

  for (int r = 0; r < R; ++r) {
    fused_mfma_kernel<false><<<rowgrid16(n_cons), 256, 0, stream>>>(
        h_con, h_var, rp + n_vars, esrc,
        wh_v2c + (size_t)r * 512, b_v2c + (size_t)r * 64,
        nullptr, nullptr, nullptr, n_cons);
    if (r == R - 1) {
      fused_mfma_kernel<true><<<rowgrid16(n_vars), 256, 0, stream>>>(
          h_var, h_con, rp, esrc,
          wh_c2v + (size_t)r * 512, b_c2v + (size_t)r * 64,
          W_ro, b_ro, (float*)d_out, n_vars);
    } else {
      fused_mfma_kernel<false><<<rowgrid16(n_vars), 256, 0, stream>>>(
          h_var, h_con, rp, esrc,
          wh_c2v + (size_t)r * 512, b_c2v + (size_t)r * 64,
          nullptr, nullptr, nullptr, n_vars);
    }
  }
}